// Round 1
// baseline (3119.092 us; speedup 1.0000x reference)
//
#include <hip/hip_runtime.h>
#include <math.h>

#define TPB 256
#define NEG_SLOPE 0.2f

static inline int cdiv_l(long a, int b){ return (int)((a + b - 1) / b); }

// order-preserving float<->uint mapping for atomicMax on floats
__device__ __forceinline__ unsigned f2o(float f){
  unsigned b = __float_as_uint(f);
  return (b & 0x80000000u) ? ~b : (b | 0x80000000u);
}
__device__ __forceinline__ float o2f(unsigned u){
  unsigned b = (u & 0x80000000u) ? (u ^ 0x80000000u) : ~u;
  return __uint_as_float(b);
}

// h = X @ W   (X: [N,Fin] row-major, W: [Fin,HC] row-major, h: [N,HC])
__global__ void gemm_k(const float* __restrict__ X, const float* __restrict__ W,
                       float* __restrict__ Hout, int N, int Fin, int HC){
  int idx = blockIdx.x * TPB + threadIdx.x;
  if (idx >= N * HC) return;
  int n = idx / HC, j = idx - n * HC;
  const float* xr = X + (size_t)n * Fin;
  float acc = 0.f;
#pragma unroll 8
  for (int k = 0; k < Fin; ++k) acc = fmaf(xr[k], W[(size_t)k * HC + j], acc);
  Hout[idx] = acc;
}

// es[n,h] = sum_c h[n,h,c]*a_src[h,c]; ed likewise
__global__ void attn_node_k(const float* __restrict__ Hf, const float* __restrict__ as_,
                            const float* __restrict__ ad_, float* __restrict__ es,
                            float* __restrict__ ed, int N, int H, int C){
  int idx = blockIdx.x * TPB + threadIdx.x;
  if (idx >= N * H) return;
  int n = idx / H, hh = idx - n * H;
  const float* hr = Hf + (size_t)n * H * C + (size_t)hh * C;
  float s = 0.f, d = 0.f;
  for (int c = 0; c < C; ++c) {
    s = fmaf(hr[c], as_[hh * C + c], s);
    d = fmaf(hr[c], ad_[hh * C + c], d);
  }
  es[idx] = s; ed[idx] = d;
}

// pass A: e = leaky_relu(es[src]+ed[dst]); store; atomicMax into per-dst max
__global__ void passA_k(const int* __restrict__ src, const int* __restrict__ dst,
                        const float* __restrict__ es, const float* __restrict__ ed,
                        float* __restrict__ exe, unsigned* __restrict__ mbits,
                        int E, int Etot, int H){
  int idx = blockIdx.x * TPB + threadIdx.x;
  if (idx >= Etot * H) return;
  int e = idx / H, hh = idx - e * H;
  int s, d;
  if (e < E) { s = src[e]; d = dst[e]; } else { s = d = e - E; }
  float v = es[s * H + hh] + ed[d * H + hh];
  v = v > 0.f ? v : v * NEG_SLOPE;
  exe[idx] = v;
  atomicMax(mbits + d * H + hh, f2o(v));
}

// pass B: ex = exp(e - m[dst]); store; atomicAdd into denom
__global__ void passB_k(const int* __restrict__ dst, float* __restrict__ exe,
                        const unsigned* __restrict__ mbits, float* __restrict__ denom,
                        int E, int Etot, int H){
  int idx = blockIdx.x * TPB + threadIdx.x;
  if (idx >= Etot * H) return;
  int e = idx / H, hh = idx - e * H;
  int d = (e < E) ? dst[e] : (e - E);
  float m = o2f(mbits[d * H + hh]);
  float ex = expf(exe[idx] - m);
  exe[idx] = ex;
  atomicAdd(denom + d * H + hh, ex);
}

__global__ void inv_k(float* __restrict__ denom, int n){
  int idx = blockIdx.x * TPB + threadIdx.x;
  if (idx >= n) return;
  denom[idx] = 1.0f / denom[idx];
}

// pass C: out[dst, c] += h[src, c] * (ex/denom[dst])
__global__ void passC_k(const int* __restrict__ src, const int* __restrict__ dst,
                        const float* __restrict__ exe, const float* __restrict__ dinv,
                        const float* __restrict__ Hf, float* __restrict__ outp,
                        int E, int Etot, int H, int HC, int logC){
  long idx = (long)blockIdx.x * TPB + threadIdx.x;
  if (idx >= (long)Etot * HC) return;
  int e = (int)(idx / HC);
  int c = (int)(idx - (long)e * HC);
  int hh = c >> logC;
  int s, d;
  if (e < E) { s = src[e]; d = dst[e]; } else { s = d = e - E; }
  float coef = exe[(size_t)e * H + hh] * dinv[(size_t)d * H + hh];
  atomicAdd(outp + (size_t)d * HC + c, Hf[(size_t)s * HC + c] * coef);
}

// out = relu(out + b)
__global__ void bias_relu_k(float* __restrict__ f, const float* __restrict__ b,
                            long n, int HCmask){
  long idx = (long)blockIdx.x * TPB + threadIdx.x;
  if (idx >= n) return;
  int c = (int)(idx & HCmask);
  float v = f[idx] + b[c];
  f[idx] = v > 0.f ? v : 0.f;
}

// pooling: atomic accumulate per-graph sums (16 channels) + counts
__global__ void pool_acc_k(const float* __restrict__ f, const int* __restrict__ batch,
                           float* __restrict__ pooled, float* __restrict__ cnt, int N){
  int idx = blockIdx.x * TPB + threadIdx.x;
  if (idx >= N * 16) return;
  int n = idx >> 4, c = idx & 15;
  int g = batch[n];
  atomicAdd(pooled + g * 16 + c, f[(size_t)n * 16 + c]);
  if (c == 0) atomicAdd(cnt + g, 1.0f);
}

__global__ void final_fc_k(const float* __restrict__ pooled, const float* __restrict__ cnt,
                           const float* __restrict__ fcW, const float* __restrict__ fcb,
                           float* __restrict__ outp){
  int g = threadIdx.x;
  if (g >= 64) return;
  float c = cnt[g]; c = c > 1.f ? c : 1.f;
  float inv = 1.0f / c;
  float acc = fcb[0];
  for (int i = 0; i < 16; ++i) acc = fmaf(pooled[g * 16 + i] * inv, fcW[i], acc);
  outp[g] = 1.0f / (1.0f + expf(-acc));
}

extern "C" void kernel_launch(void* const* d_in, const int* in_sizes, int n_in,
                              void* d_out, int out_size, void* d_ws, size_t ws_size,
                              hipStream_t stream) {
  const float* x   = (const float*)d_in[0];
  const int*  ei   = (const int*)d_in[1];
  const int*  batch= (const int*)d_in[2];

  const int N = in_sizes[0] / 128;
  const int E = in_sizes[1] / 2;
  const int Etot = E + N;

  const int* src = ei;          // edge_index[0]
  const int* dst = ei + E;      // edge_index[1]

  // per-layer params (inputs 3..22): W, as, ad, b  x5
  const float* W_[5];  const float* as_[5]; const float* ad_[5]; const float* b_[5];
  for (int l = 0; l < 5; ++l) {
    W_[l]  = (const float*)d_in[3 + 4 * l + 0];
    as_[l] = (const float*)d_in[3 + 4 * l + 1];
    ad_[l] = (const float*)d_in[3 + 4 * l + 2];
    b_[l]  = (const float*)d_in[3 + 4 * l + 3];
  }
  const float* fcW = (const float*)d_in[23];
  const float* fcb = (const float*)d_in[24];
  float* outp = (float*)d_out;

  const int FinA[5] = {128, 32, 64, 128, 64};
  const int Hh[5]   = {1, 2, 2, 2, 2};
  const int Cc[5]   = {32, 32, 64, 32, 8};
  const int logC[5] = {5, 5, 6, 5, 3};

  // workspace layout (floats)
  float* h_buf = (float*)d_ws;                        // N*128
  float* f_buf = h_buf + (size_t)N * 128;             // N*128
  float* es    = f_buf + (size_t)N * 128;             // N*2
  float* ed    = es + (size_t)N * 2;                  // N*2
  unsigned* mbits = (unsigned*)(ed + (size_t)N * 2);  // N*2
  float* denom = (float*)mbits + (size_t)N * 2;       // N*2
  float* exe   = denom + (size_t)N * 2;               // Etot*2
  float* pooled= exe + (size_t)Etot * 2;              // 64*16
  float* cnt   = pooled + 64 * 16;                    // 64

  const float* X = x;
  for (int l = 0; l < 5; ++l) {
    const int Fin = FinA[l], H = Hh[l], C = Cc[l], HC = H * C;

    gemm_k<<<cdiv_l((long)N * HC, TPB), TPB, 0, stream>>>(X, W_[l], h_buf, N, Fin, HC);
    attn_node_k<<<cdiv_l((long)N * H, TPB), TPB, 0, stream>>>(h_buf, as_[l], ad_[l], es, ed, N, H, C);

    hipMemsetAsync(mbits, 0, (size_t)N * H * 4, stream);   // f2o(-inf) < 1 for all finite
    hipMemsetAsync(denom, 0, (size_t)N * H * 4, stream);

    passA_k<<<cdiv_l((long)Etot * H, TPB), TPB, 0, stream>>>(src, dst, es, ed, exe, mbits, E, Etot, H);
    passB_k<<<cdiv_l((long)Etot * H, TPB), TPB, 0, stream>>>(dst, exe, mbits, denom, E, Etot, H);
    inv_k<<<cdiv_l((long)N * H, TPB), TPB, 0, stream>>>(denom, N * H);

    hipMemsetAsync(f_buf, 0, (size_t)N * HC * 4, stream);
    passC_k<<<cdiv_l((long)Etot * HC, TPB), TPB, 0, stream>>>(src, dst, exe, denom, h_buf, f_buf,
                                                              E, Etot, H, HC, logC[l]);
    bias_relu_k<<<cdiv_l((long)N * HC, TPB), TPB, 0, stream>>>(f_buf, b_[l], (long)N * HC, HC - 1);

    X = f_buf;  // next layer input (GEMM of next layer reads it before it's overwritten)
  }

  // global mean pool (G=64) + FC + sigmoid
  hipMemsetAsync(pooled, 0, (64 * 16 + 64) * 4, stream);
  pool_acc_k<<<cdiv_l((long)N * 16, TPB), TPB, 0, stream>>>(f_buf, batch, pooled, cnt, N);
  final_fc_k<<<1, 64, 0, stream>>>(pooled, cnt, fcW, fcb, outp);
}

// Round 2
// 1442.969 us; speedup vs baseline: 2.1616x; 2.1616x over previous
//
#include <hip/hip_runtime.h>
#include <math.h>

#define TPB 256
#define NEG_SLOPE 0.2f
#define SCAN_T 1024

static inline int cdiv_l(long a, int b){ return (int)((a + b - 1) / b); }

// ---------------- dense layers ----------------

// h = X @ W   (X: [N,Fin] row-major, W: [Fin,HC] row-major, h: [N,HC])
__global__ void gemm_k(const float* __restrict__ X, const float* __restrict__ W,
                       float* __restrict__ Hout, int N, int Fin, int HC){
  int idx = blockIdx.x * TPB + threadIdx.x;
  if (idx >= N * HC) return;
  int n = idx / HC, j = idx - n * HC;
  const float* xr = X + (size_t)n * Fin;
  float acc = 0.f;
#pragma unroll 8
  for (int k = 0; k < Fin; ++k) acc = fmaf(xr[k], W[(size_t)k * HC + j], acc);
  Hout[idx] = acc;
}

// es[n,h] = sum_c h[n,h,c]*a_src[h,c]; ed likewise
__global__ void attn_node_k(const float* __restrict__ Hf, const float* __restrict__ as_,
                            const float* __restrict__ ad_, float* __restrict__ es,
                            float* __restrict__ ed, int N, int H, int C){
  int idx = blockIdx.x * TPB + threadIdx.x;
  if (idx >= N * H) return;
  int n = idx / H, hh = idx - n * H;
  const float* hr = Hf + (size_t)n * H * C + (size_t)hh * C;
  float s = 0.f, d = 0.f;
  for (int c = 0; c < C; ++c) {
    s = fmaf(hr[c], as_[hh * C + c], s);
    d = fmaf(hr[c], ad_[hh * C + c], d);
  }
  es[idx] = s; ed[idx] = d;
}

// ---------------- CSR build (once per launch; graph static across layers) ----------------

__global__ void fill1_k(int* __restrict__ p, int n){
  int i = blockIdx.x * TPB + threadIdx.x;
  if (i < n) p[i] = 1;                 // self-loop pre-counted
}

__global__ void hist_k(const int* __restrict__ dst, int* __restrict__ count, int E){
  int i = blockIdx.x * TPB + threadIdx.x;
  if (i < E) atomicAdd(&count[dst[i]], 1);
}

// single-block exclusive scan of count[0..N) -> row_off[0..N]
__global__ void scan_k(const int* __restrict__ count, int* __restrict__ row_off, int N){
  __shared__ int part[SCAN_T];
  int t = threadIdx.x;
  int chunk = (N + SCAN_T - 1) / SCAN_T;
  int b0 = t * chunk, b1 = b0 + chunk; if (b1 > N) b1 = N; if (b0 > N) b0 = N;
  int s = 0;
  for (int i = b0; i < b1; ++i) s += count[i];
  part[t] = s; __syncthreads();
  for (int off = 1; off < SCAN_T; off <<= 1){
    int v = (t >= off) ? part[t - off] : 0;
    __syncthreads();
    part[t] += v;
    __syncthreads();
  }
  int excl = (t == 0) ? 0 : part[t - 1];
  for (int i = b0; i < b1; ++i){ row_off[i] = excl; excl += count[i]; }
  if (t == SCAN_T - 1) row_off[N] = excl;
}

// place self-loop at slot row_off[n]; cursor starts after it
__global__ void cursor_k(const int* __restrict__ row_off, int* __restrict__ cursor,
                         int* __restrict__ csr_src, int N){
  int i = blockIdx.x * TPB + threadIdx.x;
  if (i >= N) return;
  int r = row_off[i];
  csr_src[r] = i;
  cursor[i] = r + 1;
}

__global__ void scatter_k(const int* __restrict__ src, const int* __restrict__ dst,
                          int* __restrict__ cursor, int* __restrict__ csr_src, int E){
  int i = blockIdx.x * TPB + threadIdx.x;
  if (i >= E) return;
  int p = atomicAdd(&cursor[dst[i]], 1);
  csr_src[p] = src[i];
}

// ---------------- fused softmax + aggregate + bias + relu (gather, no atomics) ----------------
// one wave (64 lanes) per destination node

template<int H, int C>
__global__ __launch_bounds__(256) void agg_k(const int* __restrict__ csr_src,
        const int* __restrict__ row_off,
        const float* __restrict__ es, const float* __restrict__ ed,
        const float* __restrict__ Hf, const float* __restrict__ b,
        float* __restrict__ outp, int N){
  constexpr int HC  = H * C;
  constexpr int P   = (HC > 64) ? HC / 64 : 1;   // channels per lane
  constexpr int EPI = (HC < 64) ? 64 / HC : 1;   // edges consumed per inner step
  const int lane = threadIdx.x & 63;
  const int wv   = threadIdx.x >> 6;
  const int n = blockIdx.x * 4 + wv;
  if (n >= N) return;
  const int beg = row_off[n];
  const int deg = row_off[n + 1] - beg;

  float edn[H], m[H], sinv[H];
#pragma unroll
  for (int h = 0; h < H; ++h) edn[h] = ed[n * H + h];

  // pass 1a: per-head max over incident edges
  float mx[H];
#pragma unroll
  for (int h = 0; h < H; ++h) mx[h] = -1e30f;
  for (int j = lane; j < deg; j += 64){
    int s = csr_src[beg + j];
#pragma unroll
    for (int h = 0; h < H; ++h){
      float e = es[s * H + h] + edn[h];
      e = e > 0.f ? e : e * NEG_SLOPE;
      mx[h] = fmaxf(mx[h], e);
    }
  }
#pragma unroll
  for (int h = 0; h < H; ++h){
    float v = mx[h];
#pragma unroll
    for (int off = 32; off >= 1; off >>= 1) v = fmaxf(v, __shfl_xor(v, off));
    m[h] = v;
  }

  // pass 1b: per-head sum of exp
  float sm[H];
#pragma unroll
  for (int h = 0; h < H; ++h) sm[h] = 0.f;
  for (int j = lane; j < deg; j += 64){
    int s = csr_src[beg + j];
#pragma unroll
    for (int h = 0; h < H; ++h){
      float e = es[s * H + h] + edn[h];
      e = e > 0.f ? e : e * NEG_SLOPE;
      sm[h] += __expf(e - m[h]);
    }
  }
#pragma unroll
  for (int h = 0; h < H; ++h){
    float v = sm[h];
#pragma unroll
    for (int off = 32; off >= 1; off >>= 1) v += __shfl_xor(v, off);
    sinv[h] = 1.f / v;
  }

  // pass 2: accumulate channels
  float acc[P];
#pragma unroll
  for (int p = 0; p < P; ++p) acc[p] = 0.f;
  const int sub = (EPI > 1) ? (lane / HC) : 0;

  for (int base = 0; base < deg; base += 64){
    int j = base + lane;
    float coef[H]; int sidx = 0;
    if (j < deg){
      sidx = csr_src[beg + j];
#pragma unroll
      for (int h = 0; h < H; ++h){
        float e = es[sidx * H + h] + edn[h];
        e = e > 0.f ? e : e * NEG_SLOPE;
        coef[h] = __expf(e - m[h]) * sinv[h];
      }
    } else {
#pragma unroll
      for (int h = 0; h < H; ++h) coef[h] = 0.f;
    }
    int cnt = deg - base; if (cnt > 64) cnt = 64;
    for (int i = 0; i < cnt; i += EPI){
      int sl = i + sub;
      int sj = __shfl(sidx, sl);
      float cf[H];
#pragma unroll
      for (int h = 0; h < H; ++h) cf[h] = __shfl(coef[h], sl);
      if (EPI == 1 || sl < cnt){
        const float* hr = Hf + (size_t)sj * HC;
#pragma unroll
        for (int p = 0; p < P; ++p){
          int c = (HC > 64) ? (lane + p * 64) : (lane & (HC - 1));
          int h = c / C;
          acc[p] = fmaf(cf[h], hr[c], acc[p]);
        }
      }
    }
  }

  // cross-subslot reduction when multiple edges mapped per step
  if (EPI > 1){
#pragma unroll
    for (int p = 0; p < P; ++p){
#pragma unroll
      for (int off = HC; off < 64; off <<= 1) acc[p] += __shfl_xor(acc[p], off);
    }
  }

  if (HC >= 64 || lane < HC){
#pragma unroll
    for (int p = 0; p < P; ++p){
      int c = (HC > 64) ? (lane + p * 64) : (lane & (HC - 1));
      float v = acc[p] + b[c];
      outp[(size_t)n * HC + c] = v > 0.f ? v : 0.f;
    }
  }
}

// ---------------- pooling + FC ----------------

__global__ void pool_acc_k(const float* __restrict__ f, const int* __restrict__ batch,
                           float* __restrict__ pooled, float* __restrict__ cnt, int N){
  int idx = blockIdx.x * TPB + threadIdx.x;
  if (idx >= N * 16) return;
  int n = idx >> 4, c = idx & 15;
  int g = batch[n];
  atomicAdd(pooled + g * 16 + c, f[(size_t)n * 16 + c]);
  if (c == 0) atomicAdd(cnt + g, 1.0f);
}

__global__ void final_fc_k(const float* __restrict__ pooled, const float* __restrict__ cnt,
                           const float* __restrict__ fcW, const float* __restrict__ fcb,
                           float* __restrict__ outp){
  int g = threadIdx.x;
  if (g >= 64) return;
  float c = cnt[g]; c = c > 1.f ? c : 1.f;
  float inv = 1.0f / c;
  float acc = fcb[0];
  for (int i = 0; i < 16; ++i) acc = fmaf(pooled[g * 16 + i] * inv, fcW[i], acc);
  outp[g] = 1.0f / (1.0f + expf(-acc));
}

// ---------------- driver ----------------

extern "C" void kernel_launch(void* const* d_in, const int* in_sizes, int n_in,
                              void* d_out, int out_size, void* d_ws, size_t ws_size,
                              hipStream_t stream) {
  const float* x    = (const float*)d_in[0];
  const int*  ei    = (const int*)d_in[1];
  const int*  batch = (const int*)d_in[2];

  const int N = in_sizes[0] / 128;
  const int E = in_sizes[1] / 2;

  const int* src = ei;          // edge_index[0]
  const int* dst = ei + E;      // edge_index[1]

  const float* W_[5];  const float* as_[5]; const float* ad_[5]; const float* b_[5];
  for (int l = 0; l < 5; ++l) {
    W_[l]  = (const float*)d_in[3 + 4 * l + 0];
    as_[l] = (const float*)d_in[3 + 4 * l + 1];
    ad_[l] = (const float*)d_in[3 + 4 * l + 2];
    b_[l]  = (const float*)d_in[3 + 4 * l + 3];
  }
  const float* fcW = (const float*)d_in[23];
  const float* fcb = (const float*)d_in[24];
  float* outp = (float*)d_out;

  const int FinA[5] = {128, 32, 64, 128, 64};
  const int Hh[5]   = {1, 2, 2, 2, 2};
  const int Cc[5]   = {32, 32, 64, 32, 8};

  // workspace layout
  float* h_buf  = (float*)d_ws;                       // N*128
  float* f_buf  = h_buf + (size_t)N * 128;            // N*128
  float* es     = f_buf + (size_t)N * 128;            // N*2
  float* ed     = es + (size_t)N * 2;                 // N*2
  float* pooled = ed + (size_t)N * 2;                 // 64*16
  float* cnt    = pooled + 64 * 16;                   // 64
  int*   count  = (int*)(cnt + 64);                   // N
  int*   row_off= count + N;                          // N+1
  int*   cursor = row_off + N + 1;                    // N
  int*   csr_src= cursor + N;                         // E+N

  // ---- build CSR by destination (reused by all 5 layers) ----
  fill1_k<<<cdiv_l(N, TPB), TPB, 0, stream>>>(count, N);
  hist_k<<<cdiv_l(E, TPB), TPB, 0, stream>>>(dst, count, E);
  scan_k<<<1, SCAN_T, 0, stream>>>(count, row_off, N);
  cursor_k<<<cdiv_l(N, TPB), TPB, 0, stream>>>(row_off, cursor, csr_src, N);
  scatter_k<<<cdiv_l(E, TPB), TPB, 0, stream>>>(src, dst, cursor, csr_src, E);

  const float* X = x;
  for (int l = 0; l < 5; ++l) {
    const int Fin = FinA[l], H = Hh[l], C = Cc[l], HC = H * C;

    gemm_k<<<cdiv_l((long)N * HC, TPB), TPB, 0, stream>>>(X, W_[l], h_buf, N, Fin, HC);
    attn_node_k<<<cdiv_l((long)N * H, TPB), TPB, 0, stream>>>(h_buf, as_[l], ad_[l], es, ed, N, H, C);

    int gb = cdiv_l(N, 4);
    switch (l) {
      case 0: agg_k<1,32><<<gb, 256, 0, stream>>>(csr_src, row_off, es, ed, h_buf, b_[l], f_buf, N); break;
      case 1: agg_k<2,32><<<gb, 256, 0, stream>>>(csr_src, row_off, es, ed, h_buf, b_[l], f_buf, N); break;
      case 2: agg_k<2,64><<<gb, 256, 0, stream>>>(csr_src, row_off, es, ed, h_buf, b_[l], f_buf, N); break;
      case 3: agg_k<2,32><<<gb, 256, 0, stream>>>(csr_src, row_off, es, ed, h_buf, b_[l], f_buf, N); break;
      case 4: agg_k<2,8> <<<gb, 256, 0, stream>>>(csr_src, row_off, es, ed, h_buf, b_[l], f_buf, N); break;
    }

    X = f_buf;
  }

  // global mean pool (G=64) + FC + sigmoid
  hipMemsetAsync(pooled, 0, (64 * 16 + 64) * 4, stream);
  pool_acc_k<<<cdiv_l((long)N * 16, TPB), TPB, 0, stream>>>(f_buf, batch, pooled, cnt, N);
  final_fc_k<<<1, 64, 0, stream>>>(pooled, cnt, fcW, fcb, outp);
}

// Round 3
// 1107.311 us; speedup vs baseline: 2.8168x; 1.3031x over previous
//
#include <hip/hip_runtime.h>
#include <math.h>

#define TPB 256
#define NEG_SLOPE 0.2f
#define SCAN_T 1024

static inline int cdiv_l(long a, int b){ return (int)((a + b - 1) / b); }

// ---------------- dense layers ----------------

// h = X @ W   (X: [N,Fin] row-major, W: [Fin,HC] row-major, h: [N,HC])
__global__ void gemm_k(const float* __restrict__ X, const float* __restrict__ W,
                       float* __restrict__ Hout, int N, int Fin, int HC){
  int idx = blockIdx.x * TPB + threadIdx.x;
  if (idx >= N * HC) return;
  int n = idx / HC, j = idx - n * HC;
  const float* xr = X + (size_t)n * Fin;
  float acc = 0.f;
#pragma unroll 8
  for (int k = 0; k < Fin; ++k) acc = fmaf(xr[k], W[(size_t)k * HC + j], acc);
  Hout[idx] = acc;
}

// es[n,h] = sum_c h[n,h,c]*a_src[h,c]; ed likewise
__global__ void attn_node_k(const float* __restrict__ Hf, const float* __restrict__ as_,
                            const float* __restrict__ ad_, float* __restrict__ es,
                            float* __restrict__ ed, int N, int H, int C){
  int idx = blockIdx.x * TPB + threadIdx.x;
  if (idx >= N * H) return;
  int n = idx / H, hh = idx - n * H;
  const float* hr = Hf + (size_t)n * H * C + (size_t)hh * C;
  float s = 0.f, d = 0.f;
  for (int c = 0; c < C; ++c) {
    s = fmaf(hr[c], as_[hh * C + c], s);
    d = fmaf(hr[c], ad_[hh * C + c], d);
  }
  es[idx] = s; ed[idx] = d;
}

// ---------------- CSR build (once per launch; graph static across layers) ----------------

__global__ void fill1_k(int* __restrict__ p, int n){
  int i = blockIdx.x * TPB + threadIdx.x;
  if (i < n) p[i] = 1;                 // self-loop pre-counted
}

__global__ void hist_k(const int* __restrict__ dst, int* __restrict__ count, int E){
  int i = blockIdx.x * TPB + threadIdx.x;
  if (i < E) atomicAdd(&count[dst[i]], 1);
}

// single-block exclusive scan of count[0..N) -> row_off[0..N]
__global__ void scan_k(const int* __restrict__ count, int* __restrict__ row_off, int N){
  __shared__ int part[SCAN_T];
  int t = threadIdx.x;
  int chunk = (N + SCAN_T - 1) / SCAN_T;
  int b0 = t * chunk, b1 = b0 + chunk; if (b1 > N) b1 = N; if (b0 > N) b0 = N;
  int s = 0;
  for (int i = b0; i < b1; ++i) s += count[i];
  part[t] = s; __syncthreads();
  for (int off = 1; off < SCAN_T; off <<= 1){
    int v = (t >= off) ? part[t - off] : 0;
    __syncthreads();
    part[t] += v;
    __syncthreads();
  }
  int excl = (t == 0) ? 0 : part[t - 1];
  for (int i = b0; i < b1; ++i){ row_off[i] = excl; excl += count[i]; }
  if (t == SCAN_T - 1) row_off[N] = excl;
}

// place self-loop at slot row_off[n]; cursor starts after it
__global__ void cursor_k(const int* __restrict__ row_off, int* __restrict__ cursor,
                         int* __restrict__ csr_src, int N){
  int i = blockIdx.x * TPB + threadIdx.x;
  if (i >= N) return;
  int r = row_off[i];
  csr_src[r] = i;
  cursor[i] = r + 1;
}

__global__ void scatter_k(const int* __restrict__ src, const int* __restrict__ dst,
                          int* __restrict__ cursor, int* __restrict__ csr_src, int E){
  int i = blockIdx.x * TPB + threadIdx.x;
  if (i >= E) return;
  int p = atomicAdd(&cursor[dst[i]], 1);
  csr_src[p] = src[i];
}

// ---------------- fused softmax + aggregate + bias + relu (gather, no atomics) ----------------
// one wave (64 lanes) per destination node

template<int H, int C>
__global__ __launch_bounds__(256) void agg_k(const int* __restrict__ csr_src,
        const int* __restrict__ row_off,
        const float* __restrict__ es, const float* __restrict__ ed,
        const float* __restrict__ Hf, const float* __restrict__ b,
        float* __restrict__ outp, int N){
  constexpr int HC  = H * C;
  constexpr int P   = (HC > 64) ? HC / 64 : 1;   // channels per lane
  constexpr int EPI = (HC < 64) ? 64 / HC : 1;   // edges consumed per inner step
  const int lane = threadIdx.x & 63;
  const int wv   = threadIdx.x >> 6;
  const int n = blockIdx.x * 4 + wv;
  if (n >= N) return;
  const int beg = row_off[n];
  const int deg = row_off[n + 1] - beg;

  float edn[H], m[H], sinv[H];
#pragma unroll
  for (int h = 0; h < H; ++h) edn[h] = ed[n * H + h];

  // pass 1a: per-head max over incident edges
  float mx[H];
#pragma unroll
  for (int h = 0; h < H; ++h) mx[h] = -1e30f;
  for (int j = lane; j < deg; j += 64){
    int s = csr_src[beg + j];
#pragma unroll
    for (int h = 0; h < H; ++h){
      float e = es[s * H + h] + edn[h];
      e = e > 0.f ? e : e * NEG_SLOPE;
      mx[h] = fmaxf(mx[h], e);
    }
  }
#pragma unroll
  for (int h = 0; h < H; ++h){
    float v = mx[h];
#pragma unroll
    for (int off = 32; off >= 1; off >>= 1) v = fmaxf(v, __shfl_xor(v, off));
    m[h] = v;
  }

  // pass 1b: per-head sum of exp
  float sm[H];
#pragma unroll
  for (int h = 0; h < H; ++h) sm[h] = 0.f;
  for (int j = lane; j < deg; j += 64){
    int s = csr_src[beg + j];
#pragma unroll
    for (int h = 0; h < H; ++h){
      float e = es[s * H + h] + edn[h];
      e = e > 0.f ? e : e * NEG_SLOPE;
      sm[h] += __expf(e - m[h]);
    }
  }
#pragma unroll
  for (int h = 0; h < H; ++h){
    float v = sm[h];
#pragma unroll
    for (int off = 32; off >= 1; off >>= 1) v += __shfl_xor(v, off);
    sinv[h] = 1.f / v;
  }

  // pass 2: accumulate channels
  float acc[P];
#pragma unroll
  for (int p = 0; p < P; ++p) acc[p] = 0.f;
  const int sub = (EPI > 1) ? (lane / HC) : 0;

  for (int base = 0; base < deg; base += 64){
    int j = base + lane;
    float coef[H]; int sidx = 0;
    if (j < deg){
      sidx = csr_src[beg + j];
#pragma unroll
      for (int h = 0; h < H; ++h){
        float e = es[sidx * H + h] + edn[h];
        e = e > 0.f ? e : e * NEG_SLOPE;
        coef[h] = __expf(e - m[h]) * sinv[h];
      }
    } else {
#pragma unroll
      for (int h = 0; h < H; ++h) coef[h] = 0.f;
    }
    int cnt = deg - base; if (cnt > 64) cnt = 64;
    for (int i = 0; i < cnt; i += EPI){
      int sl = i + sub;
      int sj = __shfl(sidx, sl);
      float cf[H];
#pragma unroll
      for (int h = 0; h < H; ++h) cf[h] = __shfl(coef[h], sl);
      if (EPI == 1 || sl < cnt){
        const float* hr = Hf + (size_t)sj * HC;
#pragma unroll
        for (int p = 0; p < P; ++p){
          int c = (HC > 64) ? (lane + p * 64) : (lane & (HC - 1));
          int h = c / C;
          acc[p] = fmaf(cf[h], hr[c], acc[p]);
        }
      }
    }
  }

  // cross-subslot reduction when multiple edges mapped per step
  if (EPI > 1){
#pragma unroll
    for (int p = 0; p < P; ++p){
#pragma unroll
      for (int off = HC; off < 64; off <<= 1) acc[p] += __shfl_xor(acc[p], off);
    }
  }

  if (HC >= 64 || lane < HC){
#pragma unroll
    for (int p = 0; p < P; ++p){
      int c = (HC > 64) ? (lane + p * 64) : (lane & (HC - 1));
      float v = acc[p] + b[c];
      outp[(size_t)n * HC + c] = v > 0.f ? v : 0.f;
    }
  }
}

// ---------------- pooling + FC ----------------
// 64 blocks; block-local LDS accumulation (batch sorted => locality), one
// flush per block: each global address receives <=64 atomics instead of ~780.
__global__ __launch_bounds__(256) void pool_k(const float* __restrict__ f,
                       const int* __restrict__ batch,
                       float* __restrict__ pooled, float* __restrict__ cnt, int N){
  __shared__ float sp[64 * 16];
  __shared__ float sc[64];
  const int t = threadIdx.x;
  for (int i = t; i < 64 * 16; i += 256) sp[i] = 0.f;
  for (int i = t; i < 64; i += 256) sc[i] = 0.f;
  __syncthreads();
  const int per = (N + gridDim.x - 1) / gridDim.x;
  const int n0 = blockIdx.x * per;
  int n1 = n0 + per; if (n1 > N) n1 = N;
  const int nloc = t >> 4, c = t & 15;
  for (int n = n0 + nloc; n < n1; n += 16){
    int g = batch[n];
    atomicAdd(&sp[g * 16 + c], f[(size_t)n * 16 + c]);
    if (c == 0) atomicAdd(&sc[g], 1.f);
  }
  __syncthreads();
  for (int i = t; i < 64 * 16; i += 256) if (sp[i] != 0.f) atomicAdd(&pooled[i], sp[i]);
  for (int i = t; i < 64; i += 256)      if (sc[i] != 0.f) atomicAdd(&cnt[i], sc[i]);
}

__global__ void final_fc_k(const float* __restrict__ pooled, const float* __restrict__ cnt,
                           const float* __restrict__ fcW, const float* __restrict__ fcb,
                           float* __restrict__ outp){
  int g = threadIdx.x;
  if (g >= 64) return;
  float c = cnt[g]; c = c > 1.f ? c : 1.f;
  float inv = 1.0f / c;
  float acc = fcb[0];
  for (int i = 0; i < 16; ++i) acc = fmaf(pooled[g * 16 + i] * inv, fcW[i], acc);
  outp[g] = 1.0f / (1.0f + expf(-acc));
}

// ---------------- driver ----------------

extern "C" void kernel_launch(void* const* d_in, const int* in_sizes, int n_in,
                              void* d_out, int out_size, void* d_ws, size_t ws_size,
                              hipStream_t stream) {
  const float* x    = (const float*)d_in[0];
  const int*  ei    = (const int*)d_in[1];
  const int*  batch = (const int*)d_in[2];

  const int N = in_sizes[0] / 128;
  const int E = in_sizes[1] / 2;

  const int* src = ei;          // edge_index[0]
  const int* dst = ei + E;      // edge_index[1]

  const float* W_[5];  const float* as_[5]; const float* ad_[5]; const float* b_[5];
  for (int l = 0; l < 5; ++l) {
    W_[l]  = (const float*)d_in[3 + 4 * l + 0];
    as_[l] = (const float*)d_in[3 + 4 * l + 1];
    ad_[l] = (const float*)d_in[3 + 4 * l + 2];
    b_[l]  = (const float*)d_in[3 + 4 * l + 3];
  }
  const float* fcW = (const float*)d_in[23];
  const float* fcb = (const float*)d_in[24];
  float* outp = (float*)d_out;

  const int FinA[5] = {128, 32, 64, 128, 64};
  const int Hh[5]   = {1, 2, 2, 2, 2};
  const int Cc[5]   = {32, 32, 64, 32, 8};

  // workspace layout
  float* h_buf  = (float*)d_ws;                       // N*128
  float* f_buf  = h_buf + (size_t)N * 128;            // N*128
  float* es     = f_buf + (size_t)N * 128;            // N*2
  float* ed     = es + (size_t)N * 2;                 // N*2
  float* pooled = ed + (size_t)N * 2;                 // 64*16
  float* cnt    = pooled + 64 * 16;                   // 64
  int*   count  = (int*)(cnt + 64);                   // N
  int*   row_off= count + N;                          // N+1
  int*   cursor = row_off + N + 1;                    // N
  int*   csr_src= cursor + N;                         // E+N

  // ---- build CSR by destination (reused by all 5 layers) ----
  fill1_k<<<cdiv_l(N, TPB), TPB, 0, stream>>>(count, N);
  hist_k<<<cdiv_l(E, TPB), TPB, 0, stream>>>(dst, count, E);
  scan_k<<<1, SCAN_T, 0, stream>>>(count, row_off, N);
  cursor_k<<<cdiv_l(N, TPB), TPB, 0, stream>>>(row_off, cursor, csr_src, N);
  scatter_k<<<cdiv_l(E, TPB), TPB, 0, stream>>>(src, dst, cursor, csr_src, E);

  const float* X = x;
  for (int l = 0; l < 5; ++l) {
    const int Fin = FinA[l], H = Hh[l], C = Cc[l], HC = H * C;

    gemm_k<<<cdiv_l((long)N * HC, TPB), TPB, 0, stream>>>(X, W_[l], h_buf, N, Fin, HC);
    attn_node_k<<<cdiv_l((long)N * H, TPB), TPB, 0, stream>>>(h_buf, as_[l], ad_[l], es, ed, N, H, C);

    int gb = cdiv_l(N, 4);
    switch (l) {
      case 0: agg_k<1,32><<<gb, 256, 0, stream>>>(csr_src, row_off, es, ed, h_buf, b_[l], f_buf, N); break;
      case 1: agg_k<2,32><<<gb, 256, 0, stream>>>(csr_src, row_off, es, ed, h_buf, b_[l], f_buf, N); break;
      case 2: agg_k<2,64><<<gb, 256, 0, stream>>>(csr_src, row_off, es, ed, h_buf, b_[l], f_buf, N); break;
      case 3: agg_k<2,32><<<gb, 256, 0, stream>>>(csr_src, row_off, es, ed, h_buf, b_[l], f_buf, N); break;
      case 4: agg_k<2,8> <<<gb, 256, 0, stream>>>(csr_src, row_off, es, ed, h_buf, b_[l], f_buf, N); break;
    }

    X = f_buf;
  }

  // global mean pool (G=64) + FC + sigmoid
  hipMemsetAsync(pooled, 0, (64 * 16 + 64) * 4, stream);
  pool_k<<<64, 256, 0, stream>>>(f_buf, batch, pooled, cnt, N);
  final_fc_k<<<1, 64, 0, stream>>>(pooled, cnt, fcW, fcb, outp);
}

// Round 4
// 786.440 us; speedup vs baseline: 3.9661x; 1.4080x over previous
//
#include <hip/hip_runtime.h>
#include <math.h>

#define TPB 256
#define NEG_SLOPE 0.2f
#define SCAN_T 1024

static inline int cdiv_l(long a, int b){ return (int)((a + b - 1) / b); }

__device__ __forceinline__ ushort f2bf(float f){
  unsigned u = __float_as_uint(f);
  unsigned r = u + 0x7fffu + ((u >> 16) & 1u);   // RNE
  return (ushort)(r >> 16);
}
__device__ __forceinline__ float bf2f(unsigned hi16){ return __uint_as_float(hi16 << 16); }

// ---------------- GEMM + fused attention dots + bf16 payload write ----------------
// h[n,:] = X[n,:] @ W ; es[n,h] = h·a_src[h] ; ed[n,h] = h·a_dst[h]
// Each thread computes 4 output channels of one node. W staged in LDS.
template<int Fin, int HC, int C>
__global__ __launch_bounds__(256) void gemm2_k(const float* __restrict__ X,
        const float* __restrict__ W, const float* __restrict__ as_,
        const float* __restrict__ ad_, float* __restrict__ es, float* __restrict__ ed,
        ushort* __restrict__ Hb, int N){
  constexpr int TPN = HC / 4;         // threads per node
  constexpr int NPB = 256 / TPN;      // nodes per block
  constexpr int H   = HC / C;
  constexpr int RG  = C / 4;          // lanes per (node, head)
  __shared__ float Wl[Fin * HC];
  for (int i = threadIdx.x; i < Fin * HC; i += 256) Wl[i] = W[i];
  __syncthreads();
  const int t  = threadIdx.x;
  const int n  = blockIdx.x * NPB + t / TPN;
  const int jt = (t % TPN) * 4;
  if (n >= N) return;
  const float* xr = X + (size_t)n * Fin;
  float acc[4] = {0.f, 0.f, 0.f, 0.f};
  for (int k = 0; k < Fin; k += 4){
    float4 xv = *(const float4*)(xr + k);
#pragma unroll
    for (int kk = 0; kk < 4; ++kk){
      float xs = (&xv.x)[kk];
#pragma unroll
      for (int j = 0; j < 4; ++j)
        acc[j] = fmaf(xs, Wl[(k + kk) * HC + jt + j], acc[j]);
    }
  }
  // bf16 payload write (8B per thread, coalesced)
  ushort4 hb;
  hb.x = f2bf(acc[0]); hb.y = f2bf(acc[1]); hb.z = f2bf(acc[2]); hb.w = f2bf(acc[3]);
  *(ushort4*)(Hb + (size_t)n * HC + jt) = hb;
  // fused attention dots
  const int head = jt / C, col = jt % C;
  float ps = 0.f, pd = 0.f;
#pragma unroll
  for (int j = 0; j < 4; ++j){
    ps = fmaf(acc[j], as_[head * C + col + j], ps);
    pd = fmaf(acc[j], ad_[head * C + col + j], pd);
  }
#pragma unroll
  for (int off = RG >> 1; off >= 1; off >>= 1){
    ps += __shfl_xor(ps, off);
    pd += __shfl_xor(pd, off);
  }
  if ((t % RG) == 0){
    es[n * H + head] = ps;
    ed[n * H + head] = pd;
  }
}

// ---------------- CSR build (once per launch; graph static across layers) ----------------

__global__ void fill1_k(int* __restrict__ p, int n){
  int i = blockIdx.x * TPB + threadIdx.x;
  if (i < n) p[i] = 1;                 // self-loop pre-counted
}

__global__ void hist_k(const int* __restrict__ dst, int* __restrict__ count, int E){
  int i = blockIdx.x * TPB + threadIdx.x;
  if (i < E) atomicAdd(&count[dst[i]], 1);
}

__global__ void scan_k(const int* __restrict__ count, int* __restrict__ row_off, int N){
  __shared__ int part[SCAN_T];
  int t = threadIdx.x;
  int chunk = (N + SCAN_T - 1) / SCAN_T;
  int b0 = t * chunk, b1 = b0 + chunk; if (b1 > N) b1 = N; if (b0 > N) b0 = N;
  int s = 0;
  for (int i = b0; i < b1; ++i) s += count[i];
  part[t] = s; __syncthreads();
  for (int off = 1; off < SCAN_T; off <<= 1){
    int v = (t >= off) ? part[t - off] : 0;
    __syncthreads();
    part[t] += v;
    __syncthreads();
  }
  int excl = (t == 0) ? 0 : part[t - 1];
  for (int i = b0; i < b1; ++i){ row_off[i] = excl; excl += count[i]; }
  if (t == SCAN_T - 1) row_off[N] = excl;
}

__global__ void cursor_k(const int* __restrict__ row_off, int* __restrict__ cursor,
                         int* __restrict__ csr_src, int N){
  int i = blockIdx.x * TPB + threadIdx.x;
  if (i >= N) return;
  int r = row_off[i];
  csr_src[r] = i;          // self-loop occupies first slot
  cursor[i] = r + 1;
}

__global__ void scatter_k(const int* __restrict__ src, const int* __restrict__ dst,
                          int* __restrict__ cursor, int* __restrict__ csr_src, int E){
  int i = blockIdx.x * TPB + threadIdx.x;
  if (i >= E) return;
  int p = atomicAdd(&cursor[dst[i]], 1);
  csr_src[p] = src[i];
}

// ---------------- fused online-softmax + aggregate + bias + relu (gather) ----------------
// one wave per destination node; payload gathered in bf16, accumulated fp32

template<int H, int C>
__global__ __launch_bounds__(256) void agg_k(const int* __restrict__ csr_src,
        const int* __restrict__ row_off,
        const float* __restrict__ es, const float* __restrict__ ed,
        const ushort* __restrict__ Hb, const float* __restrict__ b,
        float* __restrict__ outp, int N){
  constexpr int HC  = H * C;
  constexpr int PW  = (HC > 64) ? 2 : 1;          // channels per lane
  constexpr int EPI = (HC < 64) ? 64 / HC : 1;    // edges per inner step
  const int lane = threadIdx.x & 63;
  const int wv   = threadIdx.x >> 6;
  const int n = blockIdx.x * 4 + wv;
  if (n >= N) return;
  const int beg = row_off[n];
  const int deg = row_off[n + 1] - beg;

  float edn[H];
#pragma unroll
  for (int h = 0; h < H; ++h) edn[h] = ed[n * H + h];

  // single-pass online softmax (max + sum)
  float m[H], sm[H];
#pragma unroll
  for (int h = 0; h < H; ++h){ m[h] = -1e30f; sm[h] = 0.f; }
  for (int j = lane; j < deg; j += 64){
    int s = csr_src[beg + j];
    float ev[H];
    if (H == 2){
      float2 e2 = *(const float2*)(es + s * 2);
      ev[0] = e2.x; if (H > 1) ev[1] = e2.y;
    } else ev[0] = es[s];
#pragma unroll
    for (int h = 0; h < H; ++h){
      float e = ev[h] + edn[h];
      e = e > 0.f ? e : e * NEG_SLOPE;
      if (e > m[h]){ sm[h] = sm[h] * __expf(m[h] - e) + 1.f; m[h] = e; }
      else sm[h] += __expf(e - m[h]);
    }
  }
  float sinv[H];
#pragma unroll
  for (int h = 0; h < H; ++h){
    float mv = m[h], sv = sm[h];
#pragma unroll
    for (int off = 32; off >= 1; off >>= 1){
      float mo = __shfl_xor(mv, off);
      float so = __shfl_xor(sv, off);
      float nm = fmaxf(mv, mo);
      sv = sv * __expf(mv - nm) + so * __expf(mo - nm);
      mv = nm;
    }
    m[h] = mv; sinv[h] = 1.f / sv;
  }

  // aggregation pass
  float acc[PW];
#pragma unroll
  for (int p = 0; p < PW; ++p) acc[p] = 0.f;
  const int sub = (EPI > 1) ? (lane / HC) : 0;

  for (int base = 0; base < deg; base += 64){
    int j = base + lane;
    float coef[H]; int sidx = 0;
    if (j < deg){
      sidx = csr_src[beg + j];
      float ev[H];
      if (H == 2){
        float2 e2 = *(const float2*)(es + sidx * 2);
        ev[0] = e2.x; if (H > 1) ev[1] = e2.y;
      } else ev[0] = es[sidx];
#pragma unroll
      for (int h = 0; h < H; ++h){
        float e = ev[h] + edn[h];
        e = e > 0.f ? e : e * NEG_SLOPE;
        coef[h] = __expf(e - m[h]) * sinv[h];
      }
    } else {
#pragma unroll
      for (int h = 0; h < H; ++h) coef[h] = 0.f;
    }
    int cnt = deg - base; if (cnt > 64) cnt = 64;
    for (int i = 0; i < cnt; i += EPI){
      int sl = i + sub;
      int sj = __shfl(sidx, sl);
      float cf[H];
#pragma unroll
      for (int h = 0; h < H; ++h) cf[h] = __shfl(coef[h], sl);
      if (EPI == 1 || sl < cnt){
        const ushort* hr = Hb + (size_t)sj * HC;
        if (PW == 2){
          unsigned v = *(const unsigned*)(hr + 2 * lane);
          int hd = lane >> 5;                    // C=64: pair within one head
          acc[0] = fmaf(cf[hd], bf2f(v & 0xffffu), acc[0]);
          acc[1] = fmaf(cf[hd], bf2f(v >> 16), acc[1]);
        } else {
          int c = lane & (HC - 1);
          acc[0] = fmaf(cf[c / C], bf2f((unsigned)hr[c]), acc[0]);
        }
      }
    }
  }

  if (EPI > 1){
#pragma unroll
    for (int off = HC; off < 64; off <<= 1) acc[0] += __shfl_xor(acc[0], off);
  }

  if (PW == 2){
    int c0 = 2 * lane;
    float2 o;
    o.x = acc[0] + b[c0];     o.x = o.x > 0.f ? o.x : 0.f;
    o.y = acc[1] + b[c0 + 1]; o.y = o.y > 0.f ? o.y : 0.f;
    *(float2*)(outp + (size_t)n * HC + c0) = o;
  } else if (lane < HC){
    float v = acc[0] + b[lane];
    outp[(size_t)n * HC + lane] = v > 0.f ? v : 0.f;
  }
}

// ---------------- pooling + FC ----------------

__global__ __launch_bounds__(256) void pool_k(const float* __restrict__ f,
                       const int* __restrict__ batch,
                       float* __restrict__ pooled, float* __restrict__ cnt, int N){
  __shared__ float sp[64 * 16];
  __shared__ float sc[64];
  const int t = threadIdx.x;
  for (int i = t; i < 64 * 16; i += 256) sp[i] = 0.f;
  for (int i = t; i < 64; i += 256) sc[i] = 0.f;
  __syncthreads();
  const int per = (N + gridDim.x - 1) / gridDim.x;
  const int n0 = blockIdx.x * per;
  int n1 = n0 + per; if (n1 > N) n1 = N;
  const int nloc = t >> 4, c = t & 15;
  for (int n = n0 + nloc; n < n1; n += 16){
    int g = batch[n];
    atomicAdd(&sp[g * 16 + c], f[(size_t)n * 16 + c]);
    if (c == 0) atomicAdd(&sc[g], 1.f);
  }
  __syncthreads();
  for (int i = t; i < 64 * 16; i += 256) if (sp[i] != 0.f) atomicAdd(&pooled[i], sp[i]);
  for (int i = t; i < 64; i += 256)      if (sc[i] != 0.f) atomicAdd(&cnt[i], sc[i]);
}

__global__ void final_fc_k(const float* __restrict__ pooled, const float* __restrict__ cnt,
                           const float* __restrict__ fcW, const float* __restrict__ fcb,
                           float* __restrict__ outp){
  int g = threadIdx.x;
  if (g >= 64) return;
  float c = cnt[g]; c = c > 1.f ? c : 1.f;
  float inv = 1.0f / c;
  float acc = fcb[0];
  for (int i = 0; i < 16; ++i) acc = fmaf(pooled[g * 16 + i] * inv, fcW[i], acc);
  outp[g] = 1.0f / (1.0f + expf(-acc));
}

// ---------------- driver ----------------

extern "C" void kernel_launch(void* const* d_in, const int* in_sizes, int n_in,
                              void* d_out, int out_size, void* d_ws, size_t ws_size,
                              hipStream_t stream) {
  const float* x    = (const float*)d_in[0];
  const int*  ei    = (const int*)d_in[1];
  const int*  batch = (const int*)d_in[2];

  const int N = in_sizes[0] / 128;
  const int E = in_sizes[1] / 2;

  const int* src = ei;
  const int* dst = ei + E;

  const float* W_[5];  const float* as_[5]; const float* ad_[5]; const float* b_[5];
  for (int l = 0; l < 5; ++l) {
    W_[l]  = (const float*)d_in[3 + 4 * l + 0];
    as_[l] = (const float*)d_in[3 + 4 * l + 1];
    ad_[l] = (const float*)d_in[3 + 4 * l + 2];
    b_[l]  = (const float*)d_in[3 + 4 * l + 3];
  }
  const float* fcW = (const float*)d_in[23];
  const float* fcb = (const float*)d_in[24];
  float* outp = (float*)d_out;

  // workspace layout
  float*  f_buf  = (float*)d_ws;                       // N*128 fp32 (layer output)
  ushort* Hb     = (ushort*)(f_buf + (size_t)N * 128); // N*128 bf16 payload
  float*  es     = (float*)(Hb + (size_t)N * 128);     // N*2
  float*  ed     = es + (size_t)N * 2;                 // N*2
  float*  pooled = ed + (size_t)N * 2;                 // 64*16
  float*  cnt    = pooled + 64 * 16;                   // 64
  int*    count  = (int*)(cnt + 64);                   // N
  int*    row_off= count + N;                          // N+1
  int*    cursor = row_off + N + 1;                    // N
  int*    csr_src= cursor + N;                         // E+N

  // ---- build CSR by destination (reused by all 5 layers) ----
  fill1_k<<<cdiv_l(N, TPB), TPB, 0, stream>>>(count, N);
  hist_k<<<cdiv_l(E, TPB), TPB, 0, stream>>>(dst, count, E);
  scan_k<<<1, SCAN_T, 0, stream>>>(count, row_off, N);
  cursor_k<<<cdiv_l(N, TPB), TPB, 0, stream>>>(row_off, cursor, csr_src, N);
  scatter_k<<<cdiv_l(E, TPB), TPB, 0, stream>>>(src, dst, cursor, csr_src, E);

  const float* X = x;
  const int gb = cdiv_l(N, 4);

  // layer 1: Fin=128, H=1, C=32
  gemm2_k<128,32,32><<<cdiv_l(N, 1024/32), 256, 0, stream>>>(X, W_[0], as_[0], ad_[0], es, ed, Hb, N);
  agg_k<1,32><<<gb, 256, 0, stream>>>(csr_src, row_off, es, ed, Hb, b_[0], f_buf, N);
  // layer 2: Fin=32, H=2, C=32
  gemm2_k<32,64,32><<<cdiv_l(N, 1024/64), 256, 0, stream>>>(f_buf, W_[1], as_[1], ad_[1], es, ed, Hb, N);
  agg_k<2,32><<<gb, 256, 0, stream>>>(csr_src, row_off, es, ed, Hb, b_[1], f_buf, N);
  // layer 3: Fin=64, H=2, C=64
  gemm2_k<64,128,64><<<cdiv_l(N, 1024/128), 256, 0, stream>>>(f_buf, W_[2], as_[2], ad_[2], es, ed, Hb, N);
  agg_k<2,64><<<gb, 256, 0, stream>>>(csr_src, row_off, es, ed, Hb, b_[2], f_buf, N);
  // layer 4: Fin=128, H=2, C=32
  gemm2_k<128,64,32><<<cdiv_l(N, 1024/64), 256, 0, stream>>>(f_buf, W_[3], as_[3], ad_[3], es, ed, Hb, N);
  agg_k<2,32><<<gb, 256, 0, stream>>>(csr_src, row_off, es, ed, Hb, b_[3], f_buf, N);
  // layer 5: Fin=64, H=2, C=8
  gemm2_k<64,16,8><<<cdiv_l(N, 1024/16), 256, 0, stream>>>(f_buf, W_[4], as_[4], ad_[4], es, ed, Hb, N);
  agg_k<2,8><<<gb, 256, 0, stream>>>(csr_src, row_off, es, ed, Hb, b_[4], f_buf, N);

  // global mean pool (G=64) + FC + sigmoid
  hipMemsetAsync(pooled, 0, (64 * 16 + 64) * 4, stream);
  pool_k<<<64, 256, 0, stream>>>(f_buf, batch, pooled, cnt, N);
  final_fc_k<<<1, 64, 0, stream>>>(pooled, cnt, fcW, fcb, outp);
}

// Round 5
// 744.879 us; speedup vs baseline: 4.1874x; 1.0558x over previous
//
#include <hip/hip_runtime.h>
#include <math.h>

#define TPB 256
#define NEG_SLOPE 0.2f
#define SCAN_T 1024
#define EPB 2048          // edges per block-chunk in sliced CSR kernels

static inline int cdiv_l(long a, int b){ return (int)((a + b - 1) / b); }

__device__ __forceinline__ ushort f2bf(float f){
  unsigned u = __float_as_uint(f);
  unsigned r = u + 0x7fffu + ((u >> 16) & 1u);   // RNE
  return (ushort)(r >> 16);
}
__device__ __forceinline__ float bf2f(unsigned hi16){ return __uint_as_float(hi16 << 16); }

// ---------------- GEMM + fused attention dots + bf16 payload write ----------------
template<int Fin, int HC, int C>
__global__ __launch_bounds__(256) void gemm2_k(const float* __restrict__ X,
        const float* __restrict__ W, const float* __restrict__ as_,
        const float* __restrict__ ad_, float* __restrict__ es, float* __restrict__ ed,
        ushort* __restrict__ Hb, int N){
  constexpr int TPN = HC / 4;         // threads per node
  constexpr int NPB = 256 / TPN;      // nodes per block
  constexpr int H   = HC / C;
  constexpr int RG  = C / 4;          // lanes per (node, head)
  __shared__ float Wl[Fin * HC];
  for (int i = threadIdx.x; i < Fin * HC; i += 256) Wl[i] = W[i];
  __syncthreads();
  const int t  = threadIdx.x;
  const int n  = blockIdx.x * NPB + t / TPN;
  const int jt = (t % TPN) * 4;
  if (n >= N) return;
  const float* xr = X + (size_t)n * Fin;
  float acc[4] = {0.f, 0.f, 0.f, 0.f};
  for (int k = 0; k < Fin; k += 4){
    float4 xv = *(const float4*)(xr + k);
#pragma unroll
    for (int kk = 0; kk < 4; ++kk){
      float xs = (&xv.x)[kk];
#pragma unroll
      for (int j = 0; j < 4; ++j)
        acc[j] = fmaf(xs, Wl[(k + kk) * HC + jt + j], acc[j]);
    }
  }
  ushort4 hb;
  hb.x = f2bf(acc[0]); hb.y = f2bf(acc[1]); hb.z = f2bf(acc[2]); hb.w = f2bf(acc[3]);
  *(ushort4*)(Hb + (size_t)n * HC + jt) = hb;
  const int head = jt / C, col = jt % C;
  float ps = 0.f, pd = 0.f;
#pragma unroll
  for (int j = 0; j < 4; ++j){
    ps = fmaf(acc[j], as_[head * C + col + j], ps);
    pd = fmaf(acc[j], ad_[head * C + col + j], pd);
  }
#pragma unroll
  for (int off = RG >> 1; off >= 1; off >>= 1){
    ps += __shfl_xor(ps, off);
    pd += __shfl_xor(pd, off);
  }
  if ((t % RG) == 0){
    es[n * H + head] = ps;
    ed[n * H + head] = pd;
  }
}

// ---------------- CSR build (XCD-sliced: writes for a dst-slice come from one XCD) ----

__global__ void fill1_k(int* __restrict__ p, int n){
  int i = blockIdx.x * TPB + threadIdx.x;
  if (i < n) p[i] = 1;                 // self-loop pre-counted
}

// block b: edge chunk b>>3, dst slice b&7. Round-robin dispatch => slice-local
// atomics stay within one XCD's L2 (heuristic; correctness independent).
__global__ __launch_bounds__(256) void hist8_k(const int* __restrict__ dst,
                        int* __restrict__ count, int E, int nps){
  const int slice = blockIdx.x & 7;
  const int lo = slice * nps, hi = lo + nps;
  const int c0 = (blockIdx.x >> 3) * EPB;
  int i1 = c0 + EPB; if (i1 > E) i1 = E;
  for (int i = c0 + threadIdx.x; i < i1; i += TPB){
    int d = dst[i];
    if (d >= lo && d < hi) atomicAdd(&count[d], 1);
  }
}

__global__ void scan_k(const int* __restrict__ count, int* __restrict__ row_off, int N){
  __shared__ int part[SCAN_T];
  int t = threadIdx.x;
  int chunk = (N + SCAN_T - 1) / SCAN_T;
  int b0 = t * chunk, b1 = b0 + chunk; if (b1 > N) b1 = N; if (b0 > N) b0 = N;
  int s = 0;
  for (int i = b0; i < b1; ++i) s += count[i];
  part[t] = s; __syncthreads();
  for (int off = 1; off < SCAN_T; off <<= 1){
    int v = (t >= off) ? part[t - off] : 0;
    __syncthreads();
    part[t] += v;
    __syncthreads();
  }
  int excl = (t == 0) ? 0 : part[t - 1];
  for (int i = b0; i < b1; ++i){ row_off[i] = excl; excl += count[i]; }
  if (t == SCAN_T - 1) row_off[N] = excl;
}

__global__ void cursor_k(const int* __restrict__ row_off, int* __restrict__ cursor,
                         int* __restrict__ csr_src, int N){
  int i = blockIdx.x * TPB + threadIdx.x;
  if (i >= N) return;
  int r = row_off[i];
  csr_src[r] = i;          // self-loop occupies first slot
  cursor[i] = r + 1;
}

__global__ __launch_bounds__(256) void scatter8_k(const int* __restrict__ src,
                          const int* __restrict__ dst,
                          int* __restrict__ cursor, int* __restrict__ csr_src,
                          int E, int nps){
  const int slice = blockIdx.x & 7;
  const int lo = slice * nps, hi = lo + nps;
  const int c0 = (blockIdx.x >> 3) * EPB;
  int i1 = c0 + EPB; if (i1 > E) i1 = E;
  for (int i = c0 + threadIdx.x; i < i1; i += TPB){
    int d = dst[i];
    if (d >= lo && d < hi){
      int p = atomicAdd(&cursor[d], 1);
      csr_src[p] = src[i];
    }
  }
}

// ---------------- fused online-softmax + aggregate + bias + relu (gather) ----------------

template<int H, int C>
__global__ __launch_bounds__(256) void agg_k(const int* __restrict__ csr_src,
        const int* __restrict__ row_off,
        const float* __restrict__ es, const float* __restrict__ ed,
        const ushort* __restrict__ Hb, const float* __restrict__ b,
        float* __restrict__ outp, int N){
  constexpr int HC  = H * C;
  constexpr int PW  = (HC > 64) ? 2 : 1;          // channels per lane
  constexpr int EPI = (HC < 64) ? 64 / HC : 1;    // edges per inner step
  const int lane = threadIdx.x & 63;
  const int wv   = threadIdx.x >> 6;
  const int n = blockIdx.x * 4 + wv;
  if (n >= N) return;
  const int beg = row_off[n];
  const int deg = row_off[n + 1] - beg;

  float edn[H];
#pragma unroll
  for (int h = 0; h < H; ++h) edn[h] = ed[n * H + h];

  float m[H], sm[H];
#pragma unroll
  for (int h = 0; h < H; ++h){ m[h] = -1e30f; sm[h] = 0.f; }
  for (int j = lane; j < deg; j += 64){
    int s = csr_src[beg + j];
    float ev[H];
    if (H == 2){
      float2 e2 = *(const float2*)(es + s * 2);
      ev[0] = e2.x; if (H > 1) ev[1] = e2.y;
    } else ev[0] = es[s];
#pragma unroll
    for (int h = 0; h < H; ++h){
      float e = ev[h] + edn[h];
      e = e > 0.f ? e : e * NEG_SLOPE;
      if (e > m[h]){ sm[h] = sm[h] * __expf(m[h] - e) + 1.f; m[h] = e; }
      else sm[h] += __expf(e - m[h]);
    }
  }
  float sinv[H];
#pragma unroll
  for (int h = 0; h < H; ++h){
    float mv = m[h], sv = sm[h];
#pragma unroll
    for (int off = 32; off >= 1; off >>= 1){
      float mo = __shfl_xor(mv, off);
      float so = __shfl_xor(sv, off);
      float nm = fmaxf(mv, mo);
      sv = sv * __expf(mv - nm) + so * __expf(mo - nm);
      mv = nm;
    }
    m[h] = mv; sinv[h] = 1.f / sv;
  }

  float acc[PW];
#pragma unroll
  for (int p = 0; p < PW; ++p) acc[p] = 0.f;
  const int sub = (EPI > 1) ? (lane / HC) : 0;

  for (int base = 0; base < deg; base += 64){
    int j = base + lane;
    float coef[H]; int sidx = 0;
    if (j < deg){
      sidx = csr_src[beg + j];
      float ev[H];
      if (H == 2){
        float2 e2 = *(const float2*)(es + sidx * 2);
        ev[0] = e2.x; if (H > 1) ev[1] = e2.y;
      } else ev[0] = es[sidx];
#pragma unroll
      for (int h = 0; h < H; ++h){
        float e = ev[h] + edn[h];
        e = e > 0.f ? e : e * NEG_SLOPE;
        coef[h] = __expf(e - m[h]) * sinv[h];
      }
    } else {
#pragma unroll
      for (int h = 0; h < H; ++h) coef[h] = 0.f;
    }
    int cnt = deg - base; if (cnt > 64) cnt = 64;
    for (int i = 0; i < cnt; i += EPI){
      int sl = i + sub;
      int sj = __shfl(sidx, sl);
      float cf[H];
#pragma unroll
      for (int h = 0; h < H; ++h) cf[h] = __shfl(coef[h], sl);
      if (EPI == 1 || sl < cnt){
        const ushort* hr = Hb + (size_t)sj * HC;
        if (PW == 2){
          unsigned v = *(const unsigned*)(hr + 2 * lane);
          int hd = lane >> 5;                    // C=64: pair within one head
          acc[0] = fmaf(cf[hd], bf2f(v & 0xffffu), acc[0]);
          acc[1] = fmaf(cf[hd], bf2f(v >> 16), acc[1]);
        } else {
          int c = lane & (HC - 1);
          acc[0] = fmaf(cf[c / C], bf2f((unsigned)hr[c]), acc[0]);
        }
      }
    }
  }

  if (EPI > 1){
#pragma unroll
    for (int off = HC; off < 64; off <<= 1) acc[0] += __shfl_xor(acc[0], off);
  }

  if (PW == 2){
    int c0 = 2 * lane;
    float2 o;
    o.x = acc[0] + b[c0];     o.x = o.x > 0.f ? o.x : 0.f;
    o.y = acc[1] + b[c0 + 1]; o.y = o.y > 0.f ? o.y : 0.f;
    *(float2*)(outp + (size_t)n * HC + c0) = o;
  } else if (lane < HC){
    float v = acc[0] + b[lane];
    outp[(size_t)n * HC + lane] = v > 0.f ? v : 0.f;
  }
}

// ---------------- pooling + FC ----------------

__global__ __launch_bounds__(256) void pool_k(const float* __restrict__ f,
                       const int* __restrict__ batch,
                       float* __restrict__ pooled, float* __restrict__ cnt, int N){
  __shared__ float sp[64 * 16];
  __shared__ float sc[64];
  const int t = threadIdx.x;
  for (int i = t; i < 64 * 16; i += 256) sp[i] = 0.f;
  for (int i = t; i < 64; i += 256) sc[i] = 0.f;
  __syncthreads();
  const int per = (N + gridDim.x - 1) / gridDim.x;
  const int n0 = blockIdx.x * per;
  int n1 = n0 + per; if (n1 > N) n1 = N;
  const int nloc = t >> 4, c = t & 15;
  for (int n = n0 + nloc; n < n1; n += 16){
    int g = batch[n];
    atomicAdd(&sp[g * 16 + c], f[(size_t)n * 16 + c]);
    if (c == 0) atomicAdd(&sc[g], 1.f);
  }
  __syncthreads();
  for (int i = t; i < 64 * 16; i += 256) if (sp[i] != 0.f) atomicAdd(&pooled[i], sp[i]);
  for (int i = t; i < 64; i += 256)      if (sc[i] != 0.f) atomicAdd(&cnt[i], sc[i]);
}

__global__ void final_fc_k(const float* __restrict__ pooled, const float* __restrict__ cnt,
                           const float* __restrict__ fcW, const float* __restrict__ fcb,
                           float* __restrict__ outp){
  int g = threadIdx.x;
  if (g >= 64) return;
  float c = cnt[g]; c = c > 1.f ? c : 1.f;
  float inv = 1.0f / c;
  float acc = fcb[0];
  for (int i = 0; i < 16; ++i) acc = fmaf(pooled[g * 16 + i] * inv, fcW[i], acc);
  outp[g] = 1.0f / (1.0f + expf(-acc));
}

// ---------------- driver ----------------

extern "C" void kernel_launch(void* const* d_in, const int* in_sizes, int n_in,
                              void* d_out, int out_size, void* d_ws, size_t ws_size,
                              hipStream_t stream) {
  const float* x    = (const float*)d_in[0];
  const int*  ei    = (const int*)d_in[1];
  const int*  batch = (const int*)d_in[2];

  const int N = in_sizes[0] / 128;
  const int E = in_sizes[1] / 2;

  const int* src = ei;
  const int* dst = ei + E;

  const float* W_[5];  const float* as_[5]; const float* ad_[5]; const float* b_[5];
  for (int l = 0; l < 5; ++l) {
    W_[l]  = (const float*)d_in[3 + 4 * l + 0];
    as_[l] = (const float*)d_in[3 + 4 * l + 1];
    ad_[l] = (const float*)d_in[3 + 4 * l + 2];
    b_[l]  = (const float*)d_in[3 + 4 * l + 3];
  }
  const float* fcW = (const float*)d_in[23];
  const float* fcb = (const float*)d_in[24];
  float* outp = (float*)d_out;

  // workspace layout
  float*  f_buf  = (float*)d_ws;                       // N*128 fp32 (layer output)
  ushort* Hb     = (ushort*)(f_buf + (size_t)N * 128); // N*128 bf16 payload
  float*  es     = (float*)(Hb + (size_t)N * 128);     // N*2
  float*  ed     = es + (size_t)N * 2;                 // N*2
  float*  pooled = ed + (size_t)N * 2;                 // 64*16
  float*  cnt    = pooled + 64 * 16;                   // 64
  int*    count  = (int*)(cnt + 64);                   // N
  int*    row_off= count + N;                          // N+1
  int*    cursor = row_off + N + 1;                    // N
  int*    csr_src= cursor + N;                         // E+N

  // ---- build CSR by destination (XCD-sliced; reused by all 5 layers) ----
  const int nps = (N + 7) / 8;                     // nodes per dst-slice
  const int nch = cdiv_l(E, EPB);                  // edge chunks
  fill1_k<<<cdiv_l(N, TPB), TPB, 0, stream>>>(count, N);
  hist8_k<<<nch * 8, TPB, 0, stream>>>(dst, count, E, nps);
  scan_k<<<1, SCAN_T, 0, stream>>>(count, row_off, N);
  cursor_k<<<cdiv_l(N, TPB), TPB, 0, stream>>>(row_off, cursor, csr_src, N);
  scatter8_k<<<nch * 8, TPB, 0, stream>>>(src, dst, cursor, csr_src, E, nps);

  const float* X = x;
  const int gb = cdiv_l(N, 4);

  // layer 1: Fin=128, H=1, C=32
  gemm2_k<128,32,32><<<cdiv_l(N, 1024/32), 256, 0, stream>>>(X, W_[0], as_[0], ad_[0], es, ed, Hb, N);
  agg_k<1,32><<<gb, 256, 0, stream>>>(csr_src, row_off, es, ed, Hb, b_[0], f_buf, N);
  // layer 2: Fin=32, H=2, C=32
  gemm2_k<32,64,32><<<cdiv_l(N, 1024/64), 256, 0, stream>>>(f_buf, W_[1], as_[1], ad_[1], es, ed, Hb, N);
  agg_k<2,32><<<gb, 256, 0, stream>>>(csr_src, row_off, es, ed, Hb, b_[1], f_buf, N);
  // layer 3: Fin=64, H=2, C=64
  gemm2_k<64,128,64><<<cdiv_l(N, 1024/128), 256, 0, stream>>>(f_buf, W_[2], as_[2], ad_[2], es, ed, Hb, N);
  agg_k<2,64><<<gb, 256, 0, stream>>>(csr_src, row_off, es, ed, Hb, b_[2], f_buf, N);
  // layer 4: Fin=128, H=2, C=32
  gemm2_k<128,64,32><<<cdiv_l(N, 1024/64), 256, 0, stream>>>(f_buf, W_[3], as_[3], ad_[3], es, ed, Hb, N);
  agg_k<2,32><<<gb, 256, 0, stream>>>(csr_src, row_off, es, ed, Hb, b_[3], f_buf, N);
  // layer 5: Fin=64, H=2, C=8
  gemm2_k<64,16,8><<<cdiv_l(N, 1024/16), 256, 0, stream>>>(f_buf, W_[4], as_[4], ad_[4], es, ed, Hb, N);
  agg_k<2,8><<<gb, 256, 0, stream>>>(csr_src, row_off, es, ed, Hb, b_[4], f_buf, N);

  // global mean pool (G=64) + FC + sigmoid
  hipMemsetAsync(pooled, 0, (64 * 16 + 64) * 4, stream);
  pool_k<<<64, 256, 0, stream>>>(f_buf, batch, pooled, cnt, N);
  final_fc_k<<<1, 64, 0, stream>>>(pooled, cnt, fcW, fcb, outp);
}

// Round 6
// 732.571 us; speedup vs baseline: 4.2577x; 1.0168x over previous
//
#include <hip/hip_runtime.h>
#include <math.h>

#define TPB 256
#define NEG_SLOPE 0.2f
#define SCAN_T 1024
#define EPB 2048          // edges per block-chunk in sliced CSR kernels

static inline int cdiv_l(long a, int b){ return (int)((a + b - 1) / b); }

__device__ __forceinline__ ushort f2bf(float f){
  unsigned u = __float_as_uint(f);
  unsigned r = u + 0x7fffu + ((u >> 16) & 1u);   // RNE
  return (ushort)(r >> 16);
}
__device__ __forceinline__ float bf2f(unsigned hi16){ return __uint_as_float(hi16 << 16); }

// ---------------- GEMM + fused attention dots + bf16 payload write ----------------
template<int Fin, int HC, int C>
__global__ __launch_bounds__(256) void gemm2_k(const float* __restrict__ X,
        const float* __restrict__ W, const float* __restrict__ as_,
        const float* __restrict__ ad_, float* __restrict__ es, float* __restrict__ ed,
        ushort* __restrict__ Hb, int N){
  constexpr int TPN = HC / 4;         // threads per node
  constexpr int NPB = 256 / TPN;      // nodes per block
  constexpr int H   = HC / C;
  constexpr int RG  = C / 4;          // lanes per (node, head)
  __shared__ float Wl[Fin * HC];
  for (int i = threadIdx.x; i < Fin * HC; i += 256) Wl[i] = W[i];
  __syncthreads();
  const int t  = threadIdx.x;
  const int n  = blockIdx.x * NPB + t / TPN;
  const int jt = (t % TPN) * 4;
  if (n >= N) return;
  const float* xr = X + (size_t)n * Fin;
  float acc[4] = {0.f, 0.f, 0.f, 0.f};
  for (int k = 0; k < Fin; k += 4){
    float4 xv = *(const float4*)(xr + k);
#pragma unroll
    for (int kk = 0; kk < 4; ++kk){
      float xs = (&xv.x)[kk];
#pragma unroll
      for (int j = 0; j < 4; ++j)
        acc[j] = fmaf(xs, Wl[(k + kk) * HC + jt + j], acc[j]);
    }
  }
  ushort4 hb;
  hb.x = f2bf(acc[0]); hb.y = f2bf(acc[1]); hb.z = f2bf(acc[2]); hb.w = f2bf(acc[3]);
  *(ushort4*)(Hb + (size_t)n * HC + jt) = hb;
  const int head = jt / C, col = jt % C;
  float ps = 0.f, pd = 0.f;
#pragma unroll
  for (int j = 0; j < 4; ++j){
    ps = fmaf(acc[j], as_[head * C + col + j], ps);
    pd = fmaf(acc[j], ad_[head * C + col + j], pd);
  }
#pragma unroll
  for (int off = RG >> 1; off >= 1; off >>= 1){
    ps += __shfl_xor(ps, off);
    pd += __shfl_xor(pd, off);
  }
  if ((t % RG) == 0){
    es[n * H + head] = ps;
    ed[n * H + head] = pd;
  }
}

// ---------------- CSR build (XCD-sliced) ----------------

__global__ void fill1_k(int* __restrict__ p, int n){
  int i = blockIdx.x * TPB + threadIdx.x;
  if (i < n) p[i] = 1;                 // self-loop pre-counted
}

__global__ __launch_bounds__(256) void hist8_k(const int* __restrict__ dst,
                        int* __restrict__ count, int E, int nps){
  const int slice = blockIdx.x & 7;
  const int lo = slice * nps, hi = lo + nps;
  const int c0 = (blockIdx.x >> 3) * EPB;
  int i1 = c0 + EPB; if (i1 > E) i1 = E;
  for (int i = c0 + threadIdx.x; i < i1; i += TPB){
    int d = dst[i];
    if (d >= lo && d < hi) atomicAdd(&count[d], 1);
  }
}

__global__ void scan_k(const int* __restrict__ count, int* __restrict__ row_off, int N){
  __shared__ int part[SCAN_T];
  int t = threadIdx.x;
  int chunk = (N + SCAN_T - 1) / SCAN_T;
  int b0 = t * chunk, b1 = b0 + chunk; if (b1 > N) b1 = N; if (b0 > N) b0 = N;
  int s = 0;
  for (int i = b0; i < b1; ++i) s += count[i];
  part[t] = s; __syncthreads();
  for (int off = 1; off < SCAN_T; off <<= 1){
    int v = (t >= off) ? part[t - off] : 0;
    __syncthreads();
    part[t] += v;
    __syncthreads();
  }
  int excl = (t == 0) ? 0 : part[t - 1];
  for (int i = b0; i < b1; ++i){ row_off[i] = excl; excl += count[i]; }
  if (t == SCAN_T - 1) row_off[N] = excl;
}

__global__ void cursor_k(const int* __restrict__ row_off, int* __restrict__ cursor,
                         int* __restrict__ csr_src, int N){
  int i = blockIdx.x * TPB + threadIdx.x;
  if (i >= N) return;
  int r = row_off[i];
  csr_src[r] = i;          // self-loop occupies first slot
  cursor[i] = r + 1;
}

__global__ __launch_bounds__(256) void scatter8_k(const int* __restrict__ src,
                          const int* __restrict__ dst,
                          int* __restrict__ cursor, int* __restrict__ csr_src,
                          int E, int nps){
  const int slice = blockIdx.x & 7;
  const int lo = slice * nps, hi = lo + nps;
  const int c0 = (blockIdx.x >> 3) * EPB;
  int i1 = c0 + EPB; if (i1 > E) i1 = E;
  for (int i = c0 + threadIdx.x; i < i1; i += TPB){
    int d = dst[i];
    if (d >= lo && d < hi){
      int p = atomicAdd(&cursor[d], 1);
      csr_src[p] = src[i];
    }
  }
}

// ---------------- fused online-softmax + aggregate + bias + relu (gather) ----------------
// one wave per destination node; bf16 payload, fp32 accumulate.
// EPI==1 path: edge index uniform per wave -> v_readlane broadcast (SGPR, no DS)
// and scalar-base gather loads.

template<int H, int C>
__global__ __launch_bounds__(256) void agg_k(const int* __restrict__ csr_src,
        const int* __restrict__ row_off,
        const float* __restrict__ es, const float* __restrict__ ed,
        const ushort* __restrict__ Hb, const float* __restrict__ b,
        float* __restrict__ outp, int N){
  constexpr int HC  = H * C;
  constexpr int PW  = (HC > 64) ? 2 : 1;          // channels per lane
  constexpr int EPI = (HC < 64) ? 64 / HC : 1;    // edges per inner step
  const int lane = threadIdx.x & 63;
  const int wv   = threadIdx.x >> 6;
  const int n = blockIdx.x * 4 + wv;
  if (n >= N) return;
  const int beg = row_off[n];
  const int deg = row_off[n + 1] - beg;

  float edn[H];
#pragma unroll
  for (int h = 0; h < H; ++h) edn[h] = ed[n * H + h];

  // single-pass online softmax (max + sum)
  float m[H], sm[H];
#pragma unroll
  for (int h = 0; h < H; ++h){ m[h] = -1e30f; sm[h] = 0.f; }
  for (int j = lane; j < deg; j += 64){
    int s = csr_src[beg + j];
    float ev[H];
    if (H == 2){
      float2 e2 = *(const float2*)(es + s * 2);
      ev[0] = e2.x; ev[1] = e2.y;
    } else ev[0] = es[s];
#pragma unroll
    for (int h = 0; h < H; ++h){
      float e = ev[h] + edn[h];
      e = e > 0.f ? e : e * NEG_SLOPE;
      if (e > m[h]){ sm[h] = sm[h] * __expf(m[h] - e) + 1.f; m[h] = e; }
      else sm[h] += __expf(e - m[h]);
    }
  }
  float sinv[H];
#pragma unroll
  for (int h = 0; h < H; ++h){
    float mv = m[h], sv = sm[h];
#pragma unroll
    for (int off = 32; off >= 1; off >>= 1){
      float mo = __shfl_xor(mv, off);
      float so = __shfl_xor(sv, off);
      float nm = fmaxf(mv, mo);
      sv = sv * __expf(mv - nm) + so * __expf(mo - nm);
      mv = nm;
    }
    m[h] = mv; sinv[h] = 1.f / sv;
  }

  float acc[PW];
#pragma unroll
  for (int p = 0; p < PW; ++p) acc[p] = 0.f;
  const int sub = (EPI > 1) ? (lane / HC) : 0;

  for (int base = 0; base < deg; base += 64){
    int j = base + lane;
    float coef[H]; int sidx = 0;
    if (j < deg){
      sidx = csr_src[beg + j];
      float ev[H];
      if (H == 2){
        float2 e2 = *(const float2*)(es + sidx * 2);
        ev[0] = e2.x; ev[1] = e2.y;
      } else ev[0] = es[sidx];
#pragma unroll
      for (int h = 0; h < H; ++h){
        float e = ev[h] + edn[h];
        e = e > 0.f ? e : e * NEG_SLOPE;
        coef[h] = __expf(e - m[h]) * sinv[h];
      }
    } else {
#pragma unroll
      for (int h = 0; h < H; ++h) coef[h] = 0.f;
    }
    int cnt = deg - base; if (cnt > 64) cnt = 64;

    if constexpr (EPI == 1){
      // uniform edge index: readlane broadcast (SGPR), scalar-base gather
#pragma unroll 4
      for (int i = 0; i < cnt; ++i){
        int sj = __builtin_amdgcn_readlane(sidx, i);
        float cf[H];
#pragma unroll
        for (int h = 0; h < H; ++h)
          cf[h] = __int_as_float(__builtin_amdgcn_readlane(__float_as_int(coef[h]), i));
        const ushort* hr = Hb + (size_t)sj * HC;
        if (PW == 2){
          unsigned v = *(const unsigned*)(hr + 2 * lane);
          int hd = lane >> 5;                    // HC=128: head per half-wave
          acc[0] = fmaf(cf[hd], bf2f(v & 0xffffu), acc[0]);
          acc[1] = fmaf(cf[hd], bf2f(v >> 16), acc[1]);
        } else {
          int c = lane;                          // HC=64
          acc[0] = fmaf(cf[c / C], bf2f((unsigned)hr[c]), acc[0]);
        }
      }
    } else {
      for (int i = 0; i < cnt; i += EPI){
        int sl = i + sub;
        int sj = __shfl(sidx, sl);
        float cf[H];
#pragma unroll
        for (int h = 0; h < H; ++h) cf[h] = __shfl(coef[h], sl);
        if (sl < cnt){
          const ushort* hr = Hb + (size_t)sj * HC;
          int c = lane & (HC - 1);
          acc[0] = fmaf(cf[c / C], bf2f((unsigned)hr[c]), acc[0]);
        }
      }
    }
  }

  if (EPI > 1){
#pragma unroll
    for (int off = HC; off < 64; off <<= 1) acc[0] += __shfl_xor(acc[0], off);
  }

  if (PW == 2){
    int c0 = 2 * lane;
    float2 o;
    o.x = acc[0] + b[c0];     o.x = o.x > 0.f ? o.x : 0.f;
    o.y = acc[1] + b[c0 + 1]; o.y = o.y > 0.f ? o.y : 0.f;
    *(float2*)(outp + (size_t)n * HC + c0) = o;
  } else if (HC == 64 || lane < HC){
    float v = acc[0] + b[lane & (HC - 1)];
    if (EPI == 1 || lane < HC)
      outp[(size_t)n * HC + (lane & (HC - 1))] = v > 0.f ? v : 0.f;
  }
}

// ---------------- pooling + FC ----------------

__global__ __launch_bounds__(256) void pool_k(const float* __restrict__ f,
                       const int* __restrict__ batch,
                       float* __restrict__ pooled, float* __restrict__ cnt, int N){
  __shared__ float sp[64 * 16];
  __shared__ float sc[64];
  const int t = threadIdx.x;
  for (int i = t; i < 64 * 16; i += 256) sp[i] = 0.f;
  for (int i = t; i < 64; i += 256) sc[i] = 0.f;
  __syncthreads();
  const int per = (N + gridDim.x - 1) / gridDim.x;
  const int n0 = blockIdx.x * per;
  int n1 = n0 + per; if (n1 > N) n1 = N;
  const int nloc = t >> 4, c = t & 15;
  for (int n = n0 + nloc; n < n1; n += 16){
    int g = batch[n];
    atomicAdd(&sp[g * 16 + c], f[(size_t)n * 16 + c]);
    if (c == 0) atomicAdd(&sc[g], 1.f);
  }
  __syncthreads();
  for (int i = t; i < 64 * 16; i += 256) if (sp[i] != 0.f) atomicAdd(&pooled[i], sp[i]);
  for (int i = t; i < 64; i += 256)      if (sc[i] != 0.f) atomicAdd(&cnt[i], sc[i]);
}

__global__ void final_fc_k(const float* __restrict__ pooled, const float* __restrict__ cnt,
                           const float* __restrict__ fcW, const float* __restrict__ fcb,
                           float* __restrict__ outp){
  int g = threadIdx.x;
  if (g >= 64) return;
  float c = cnt[g]; c = c > 1.f ? c : 1.f;
  float inv = 1.0f / c;
  float acc = fcb[0];
  for (int i = 0; i < 16; ++i) acc = fmaf(pooled[g * 16 + i] * inv, fcW[i], acc);
  outp[g] = 1.0f / (1.0f + expf(-acc));
}

// ---------------- driver ----------------

extern "C" void kernel_launch(void* const* d_in, const int* in_sizes, int n_in,
                              void* d_out, int out_size, void* d_ws, size_t ws_size,
                              hipStream_t stream) {
  const float* x    = (const float*)d_in[0];
  const int*  ei    = (const int*)d_in[1];
  const int*  batch = (const int*)d_in[2];

  const int N = in_sizes[0] / 128;
  const int E = in_sizes[1] / 2;

  const int* src = ei;
  const int* dst = ei + E;

  const float* W_[5];  const float* as_[5]; const float* ad_[5]; const float* b_[5];
  for (int l = 0; l < 5; ++l) {
    W_[l]  = (const float*)d_in[3 + 4 * l + 0];
    as_[l] = (const float*)d_in[3 + 4 * l + 1];
    ad_[l] = (const float*)d_in[3 + 4 * l + 2];
    b_[l]  = (const float*)d_in[3 + 4 * l + 3];
  }
  const float* fcW = (const float*)d_in[23];
  const float* fcb = (const float*)d_in[24];
  float* outp = (float*)d_out;

  // workspace layout
  float*  f_buf  = (float*)d_ws;                       // N*128 fp32 (layer output)
  ushort* Hb     = (ushort*)(f_buf + (size_t)N * 128); // N*128 bf16 payload
  float*  es     = (float*)(Hb + (size_t)N * 128);     // N*2
  float*  ed     = es + (size_t)N * 2;                 // N*2
  float*  pooled = ed + (size_t)N * 2;                 // 64*16
  float*  cnt    = pooled + 64 * 16;                   // 64
  int*    count  = (int*)(cnt + 64);                   // N
  int*    row_off= count + N;                          // N+1
  int*    cursor = row_off + N + 1;                    // N
  int*    csr_src= cursor + N;                         // E+N

  // ---- build CSR by destination (XCD-sliced; reused by all 5 layers) ----
  const int nps = (N + 7) / 8;                     // nodes per dst-slice
  const int nch = cdiv_l(E, EPB);                  // edge chunks
  fill1_k<<<cdiv_l(N, TPB), TPB, 0, stream>>>(count, N);
  hist8_k<<<nch * 8, TPB, 0, stream>>>(dst, count, E, nps);
  scan_k<<<1, SCAN_T, 0, stream>>>(count, row_off, N);
  cursor_k<<<cdiv_l(N, TPB), TPB, 0, stream>>>(row_off, cursor, csr_src, N);
  scatter8_k<<<nch * 8, TPB, 0, stream>>>(src, dst, cursor, csr_src, E, nps);

  const float* X = x;
  const int gb = cdiv_l(N, 4);

  // layer 1: Fin=128, H=1, C=32
  gemm2_k<128,32,32><<<cdiv_l(N, 1024/32), 256, 0, stream>>>(X, W_[0], as_[0], ad_[0], es, ed, Hb, N);
  agg_k<1,32><<<gb, 256, 0, stream>>>(csr_src, row_off, es, ed, Hb, b_[0], f_buf, N);
  // layer 2: Fin=32, H=2, C=32
  gemm2_k<32,64,32><<<cdiv_l(N, 1024/64), 256, 0, stream>>>(f_buf, W_[1], as_[1], ad_[1], es, ed, Hb, N);
  agg_k<2,32><<<gb, 256, 0, stream>>>(csr_src, row_off, es, ed, Hb, b_[1], f_buf, N);
  // layer 3: Fin=64, H=2, C=64
  gemm2_k<64,128,64><<<cdiv_l(N, 1024/128), 256, 0, stream>>>(f_buf, W_[2], as_[2], ad_[2], es, ed, Hb, N);
  agg_k<2,64><<<gb, 256, 0, stream>>>(csr_src, row_off, es, ed, Hb, b_[2], f_buf, N);
  // layer 4: Fin=128, H=2, C=32
  gemm2_k<128,64,32><<<cdiv_l(N, 1024/64), 256, 0, stream>>>(f_buf, W_[3], as_[3], ad_[3], es, ed, Hb, N);
  agg_k<2,32><<<gb, 256, 0, stream>>>(csr_src, row_off, es, ed, Hb, b_[3], f_buf, N);
  // layer 5: Fin=64, H=2, C=8
  gemm2_k<64,16,8><<<cdiv_l(N, 1024/16), 256, 0, stream>>>(f_buf, W_[4], as_[4], ad_[4], es, ed, Hb, N);
  agg_k<2,8><<<gb, 256, 0, stream>>>(csr_src, row_off, es, ed, Hb, b_[4], f_buf, N);

  // global mean pool (G=64) + FC + sigmoid
  hipMemsetAsync(pooled, 0, (64 * 16 + 64) * 4, stream);
  pool_k<<<64, 256, 0, stream>>>(f_buf, batch, pooled, cnt, N);
  final_fc_k<<<1, 64, 0, stream>>>(pooled, cnt, fcW, fcb, outp);
}

// Round 7
// 693.030 us; speedup vs baseline: 4.5007x; 1.0571x over previous
//
#include <hip/hip_runtime.h>
#include <math.h>

#define TPB 256
#define NEG_SLOPE 0.2f
#define SCAN_T 1024
#define EPB 2048          // edges per block-chunk in sliced CSR kernels

static inline int cdiv_l(long a, int b){ return (int)((a + b - 1) / b); }

__device__ __forceinline__ ushort f2bf(float f){
  unsigned u = __float_as_uint(f);
  unsigned r = u + 0x7fffu + ((u >> 16) & 1u);   // RNE
  return (ushort)(r >> 16);
}
__device__ __forceinline__ float bf2f(unsigned hi16){ return __uint_as_float(hi16 << 16); }

// ---------------- GEMM + fused attention dots + bf16 payload write ----------------
template<int Fin, int HC, int C>
__global__ __launch_bounds__(256) void gemm2_k(const float* __restrict__ X,
        const float* __restrict__ W, const float* __restrict__ as_,
        const float* __restrict__ ad_, float* __restrict__ es, float* __restrict__ ed,
        ushort* __restrict__ Hb, int N){
  constexpr int TPN = HC / 4;         // threads per node
  constexpr int NPB = 256 / TPN;      // nodes per block
  constexpr int H   = HC / C;
  constexpr int RG  = C / 4;          // lanes per (node, head)
  __shared__ float Wl[Fin * HC];
  for (int i = threadIdx.x; i < Fin * HC; i += 256) Wl[i] = W[i];
  __syncthreads();
  const int t  = threadIdx.x;
  const int n  = blockIdx.x * NPB + t / TPN;
  const int jt = (t % TPN) * 4;
  if (n >= N) return;
  const float* xr = X + (size_t)n * Fin;
  float acc[4] = {0.f, 0.f, 0.f, 0.f};
  for (int k = 0; k < Fin; k += 4){
    float4 xv = *(const float4*)(xr + k);
#pragma unroll
    for (int kk = 0; kk < 4; ++kk){
      float xs = (&xv.x)[kk];
#pragma unroll
      for (int j = 0; j < 4; ++j)
        acc[j] = fmaf(xs, Wl[(k + kk) * HC + jt + j], acc[j]);
    }
  }
  ushort4 hb;
  hb.x = f2bf(acc[0]); hb.y = f2bf(acc[1]); hb.z = f2bf(acc[2]); hb.w = f2bf(acc[3]);
  *(ushort4*)(Hb + (size_t)n * HC + jt) = hb;
  const int head = jt / C, col = jt % C;
  float ps = 0.f, pd = 0.f;
#pragma unroll
  for (int j = 0; j < 4; ++j){
    ps = fmaf(acc[j], as_[head * C + col + j], ps);
    pd = fmaf(acc[j], ad_[head * C + col + j], pd);
  }
#pragma unroll
  for (int off = RG >> 1; off >= 1; off >>= 1){
    ps += __shfl_xor(ps, off);
    pd += __shfl_xor(pd, off);
  }
  if ((t % RG) == 0){
    es[n * H + head] = ps;
    ed[n * H + head] = pd;
  }
}

// ---------------- CSR build (XCD-sliced) ----------------

__global__ void fill1_k(int* __restrict__ p, int n){
  int i = blockIdx.x * TPB + threadIdx.x;
  if (i < n) p[i] = 1;                 // self-loop pre-counted
}

__global__ __launch_bounds__(256) void hist8_k(const int* __restrict__ dst,
                        int* __restrict__ count, int E, int nps){
  const int slice = blockIdx.x & 7;
  const int lo = slice * nps, hi = lo + nps;
  const int c0 = (blockIdx.x >> 3) * EPB;
  int i1 = c0 + EPB; if (i1 > E) i1 = E;
  for (int i = c0 + threadIdx.x; i < i1; i += TPB){
    int d = dst[i];
    if (d >= lo && d < hi) atomicAdd(&count[d], 1);
  }
}

__global__ void scan_k(const int* __restrict__ count, int* __restrict__ row_off, int N){
  __shared__ int part[SCAN_T];
  int t = threadIdx.x;
  int chunk = (N + SCAN_T - 1) / SCAN_T;
  int b0 = t * chunk, b1 = b0 + chunk; if (b1 > N) b1 = N; if (b0 > N) b0 = N;
  int s = 0;
  for (int i = b0; i < b1; ++i) s += count[i];
  part[t] = s; __syncthreads();
  for (int off = 1; off < SCAN_T; off <<= 1){
    int v = (t >= off) ? part[t - off] : 0;
    __syncthreads();
    part[t] += v;
    __syncthreads();
  }
  int excl = (t == 0) ? 0 : part[t - 1];
  for (int i = b0; i < b1; ++i){ row_off[i] = excl; excl += count[i]; }
  if (t == SCAN_T - 1) row_off[N] = excl;
}

__global__ void cursor_k(const int* __restrict__ row_off, int* __restrict__ cursor,
                         int* __restrict__ csr_src, int N){
  int i = blockIdx.x * TPB + threadIdx.x;
  if (i >= N) return;
  int r = row_off[i];
  csr_src[r] = i;          // self-loop occupies first slot
  cursor[i] = r + 1;
}

__global__ __launch_bounds__(256) void scatter8_k(const int* __restrict__ src,
                          const int* __restrict__ dst,
                          int* __restrict__ cursor, int* __restrict__ csr_src,
                          int E, int nps){
  const int slice = blockIdx.x & 7;
  const int lo = slice * nps, hi = lo + nps;
  const int c0 = (blockIdx.x >> 3) * EPB;
  int i1 = c0 + EPB; if (i1 > E) i1 = E;
  for (int i = c0 + threadIdx.x; i < i1; i += TPB){
    int d = dst[i];
    if (d >= lo && d < hi){
      int p = atomicAdd(&cursor[d], 1);
      csr_src[p] = src[i];
    }
  }
}

// ---------------- fused single-pass softmax + aggregate + bias + relu ----------------
// one wave per destination node; bf16 payload, fp32 accumulate.
// Softmax without max-subtraction (shift-invariant; logits clamped at 80 so
// exp can't overflow): t = exp(leaky(es+ed)); acc += t*h_row; den += t;
// out = acc/den + bias. Single pass over the edge list.

template<int H, int C>
__global__ __launch_bounds__(256) void agg_k(const int* __restrict__ csr_src,
        const int* __restrict__ row_off,
        const float* __restrict__ es, const float* __restrict__ ed,
        const ushort* __restrict__ Hb, const float* __restrict__ b,
        float* __restrict__ outp, int N){
  constexpr int HC  = H * C;
  constexpr int PW  = (HC > 64) ? 2 : 1;          // channels per lane
  constexpr int EPI = (HC < 64) ? 64 / HC : 1;    // edges per inner step
  const int lane = threadIdx.x & 63;
  const int wv   = threadIdx.x >> 6;
  const int n = blockIdx.x * 4 + wv;
  if (n >= N) return;
  const int beg = row_off[n];
  const int deg = row_off[n + 1] - beg;

  float edn[H];
#pragma unroll
  for (int h = 0; h < H; ++h) edn[h] = ed[n * H + h];

  float acc[PW];
#pragma unroll
  for (int p = 0; p < PW; ++p) acc[p] = 0.f;
  float den[H];
#pragma unroll
  for (int h = 0; h < H; ++h) den[h] = 0.f;
  const int sub = (EPI > 1) ? (lane / HC) : 0;

  for (int base = 0; base < deg; base += 64){
    int j = base + lane;
    float t[H]; int sidx = 0;
    if (j < deg){
      sidx = csr_src[beg + j];
      float ev[H];
      if (H == 2){
        float2 e2 = *(const float2*)(es + sidx * 2);
        ev[0] = e2.x; ev[1] = e2.y;
      } else ev[0] = es[sidx];
#pragma unroll
      for (int h = 0; h < H; ++h){
        float e = ev[h] + edn[h];
        e = e > 0.f ? e : e * NEG_SLOPE;
        e = fminf(e, 80.f);
        t[h] = __expf(e);
        den[h] += t[h];
      }
    } else {
#pragma unroll
      for (int h = 0; h < H; ++h) t[h] = 0.f;
    }
    int cnt = deg - base; if (cnt > 64) cnt = 64;

    if constexpr (EPI == 1){
      // uniform edge index: readlane broadcast (SGPR), scalar-base gather
#pragma unroll 4
      for (int i = 0; i < cnt; ++i){
        int sj = __builtin_amdgcn_readlane(sidx, i);
        float tf[H];
#pragma unroll
        for (int h = 0; h < H; ++h)
          tf[h] = __int_as_float(__builtin_amdgcn_readlane(__float_as_int(t[h]), i));
        const ushort* hr = Hb + (size_t)sj * HC;
        if (PW == 2){
          unsigned v = *(const unsigned*)(hr + 2 * lane);
          int hd = lane >> 5;                    // HC=128: channel pair's head
          acc[0] = fmaf(tf[hd], bf2f(v & 0xffffu), acc[0]);
          acc[1] = fmaf(tf[hd], bf2f(v >> 16), acc[1]);
        } else {
          acc[0] = fmaf(tf[lane / C], bf2f((unsigned)hr[lane]), acc[0]);
        }
      }
    } else {
      for (int i = 0; i < cnt; i += EPI){
        int sl = i + sub;
        int sj = __shfl(sidx, sl);
        float tf[H];
#pragma unroll
        for (int h = 0; h < H; ++h) tf[h] = __shfl(t[h], sl);
        if (sl < cnt){
          const ushort* hr = Hb + (size_t)sj * HC;
          int c = lane & (HC - 1);
          acc[0] = fmaf(tf[c / C], bf2f((unsigned)hr[c]), acc[0]);
        }
      }
    }
  }

  // wave-reduce denominators
  float sinv[H];
#pragma unroll
  for (int h = 0; h < H; ++h){
    float v = den[h];
#pragma unroll
    for (int off = 32; off >= 1; off >>= 1) v += __shfl_xor(v, off);
    sinv[h] = 1.f / v;
  }

  if (EPI > 1){
#pragma unroll
    for (int off = HC; off < 64; off <<= 1) acc[0] += __shfl_xor(acc[0], off);
  }

  if (PW == 2){
    int c0 = 2 * lane, hd = lane >> 5;
    float2 o;
    o.x = fmaf(acc[0], sinv[hd], b[c0]);     o.x = o.x > 0.f ? o.x : 0.f;
    o.y = fmaf(acc[1], sinv[hd], b[c0 + 1]); o.y = o.y > 0.f ? o.y : 0.f;
    *(float2*)(outp + (size_t)n * HC + c0) = o;
  } else if (EPI == 1){                      // HC == 64
    float v = fmaf(acc[0], sinv[lane / C], b[lane]);
    outp[(size_t)n * HC + lane] = v > 0.f ? v : 0.f;
  } else if (lane < HC){
    float v = fmaf(acc[0], sinv[lane / C], b[lane]);
    outp[(size_t)n * HC + lane] = v > 0.f ? v : 0.f;
  }
}

// ---------------- pooling + FC ----------------

__global__ __launch_bounds__(256) void pool_k(const float* __restrict__ f,
                       const int* __restrict__ batch,
                       float* __restrict__ pooled, float* __restrict__ cnt, int N){
  __shared__ float sp[64 * 16];
  __shared__ float sc[64];
  const int t = threadIdx.x;
  for (int i = t; i < 64 * 16; i += 256) sp[i] = 0.f;
  for (int i = t; i < 64; i += 256) sc[i] = 0.f;
  __syncthreads();
  const int per = (N + gridDim.x - 1) / gridDim.x;
  const int n0 = blockIdx.x * per;
  int n1 = n0 + per; if (n1 > N) n1 = N;
  const int nloc = t >> 4, c = t & 15;
  for (int n = n0 + nloc; n < n1; n += 16){
    int g = batch[n];
    atomicAdd(&sp[g * 16 + c], f[(size_t)n * 16 + c]);
    if (c == 0) atomicAdd(&sc[g], 1.f);
  }
  __syncthreads();
  for (int i = t; i < 64 * 16; i += 256) if (sp[i] != 0.f) atomicAdd(&pooled[i], sp[i]);
  for (int i = t; i < 64; i += 256)      if (sc[i] != 0.f) atomicAdd(&cnt[i], sc[i]);
}

__global__ void final_fc_k(const float* __restrict__ pooled, const float* __restrict__ cnt,
                           const float* __restrict__ fcW, const float* __restrict__ fcb,
                           float* __restrict__ outp){
  int g = threadIdx.x;
  if (g >= 64) return;
  float c = cnt[g]; c = c > 1.f ? c : 1.f;
  float inv = 1.0f / c;
  float acc = fcb[0];
  for (int i = 0; i < 16; ++i) acc = fmaf(pooled[g * 16 + i] * inv, fcW[i], acc);
  outp[g] = 1.0f / (1.0f + expf(-acc));
}

// ---------------- driver ----------------

extern "C" void kernel_launch(void* const* d_in, const int* in_sizes, int n_in,
                              void* d_out, int out_size, void* d_ws, size_t ws_size,
                              hipStream_t stream) {
  const float* x    = (const float*)d_in[0];
  const int*  ei    = (const int*)d_in[1];
  const int*  batch = (const int*)d_in[2];

  const int N = in_sizes[0] / 128;
  const int E = in_sizes[1] / 2;

  const int* src = ei;
  const int* dst = ei + E;

  const float* W_[5];  const float* as_[5]; const float* ad_[5]; const float* b_[5];
  for (int l = 0; l < 5; ++l) {
    W_[l]  = (const float*)d_in[3 + 4 * l + 0];
    as_[l] = (const float*)d_in[3 + 4 * l + 1];
    ad_[l] = (const float*)d_in[3 + 4 * l + 2];
    b_[l]  = (const float*)d_in[3 + 4 * l + 3];
  }
  const float* fcW = (const float*)d_in[23];
  const float* fcb = (const float*)d_in[24];
  float* outp = (float*)d_out;

  // workspace layout
  float*  f_buf  = (float*)d_ws;                       // N*128 fp32 (layer output)
  ushort* Hb     = (ushort*)(f_buf + (size_t)N * 128); // N*128 bf16 payload
  float*  es     = (float*)(Hb + (size_t)N * 128);     // N*2
  float*  ed     = es + (size_t)N * 2;                 // N*2
  float*  pooled = ed + (size_t)N * 2;                 // 64*16
  float*  cnt    = pooled + 64 * 16;                   // 64
  int*    count  = (int*)(cnt + 64);                   // N
  int*    row_off= count + N;                          // N+1
  int*    cursor = row_off + N + 1;                    // N
  int*    csr_src= cursor + N;                         // E+N

  // ---- build CSR by destination (XCD-sliced; reused by all 5 layers) ----
  const int nps = (N + 7) / 8;                     // nodes per dst-slice
  const int nch = cdiv_l(E, EPB);                  // edge chunks
  fill1_k<<<cdiv_l(N, TPB), TPB, 0, stream>>>(count, N);
  hist8_k<<<nch * 8, TPB, 0, stream>>>(dst, count, E, nps);
  scan_k<<<1, SCAN_T, 0, stream>>>(count, row_off, N);
  cursor_k<<<cdiv_l(N, TPB), TPB, 0, stream>>>(row_off, cursor, csr_src, N);
  scatter8_k<<<nch * 8, TPB, 0, stream>>>(src, dst, cursor, csr_src, E, nps);

  const float* X = x;
  const int gb = cdiv_l(N, 4);

  // layer 1: Fin=128, H=1, C=32
  gemm2_k<128,32,32><<<cdiv_l(N, 1024/32), 256, 0, stream>>>(X, W_[0], as_[0], ad_[0], es, ed, Hb, N);
  agg_k<1,32><<<gb, 256, 0, stream>>>(csr_src, row_off, es, ed, Hb, b_[0], f_buf, N);
  // layer 2: Fin=32, H=2, C=32
  gemm2_k<32,64,32><<<cdiv_l(N, 1024/64), 256, 0, stream>>>(f_buf, W_[1], as_[1], ad_[1], es, ed, Hb, N);
  agg_k<2,32><<<gb, 256, 0, stream>>>(csr_src, row_off, es, ed, Hb, b_[1], f_buf, N);
  // layer 3: Fin=64, H=2, C=64
  gemm2_k<64,128,64><<<cdiv_l(N, 1024/128), 256, 0, stream>>>(f_buf, W_[2], as_[2], ad_[2], es, ed, Hb, N);
  agg_k<2,64><<<gb, 256, 0, stream>>>(csr_src, row_off, es, ed, Hb, b_[2], f_buf, N);
  // layer 4: Fin=128, H=2, C=32
  gemm2_k<128,64,32><<<cdiv_l(N, 1024/64), 256, 0, stream>>>(f_buf, W_[3], as_[3], ad_[3], es, ed, Hb, N);
  agg_k<2,32><<<gb, 256, 0, stream>>>(csr_src, row_off, es, ed, Hb, b_[3], f_buf, N);
  // layer 5: Fin=64, H=2, C=8
  gemm2_k<64,16,8><<<cdiv_l(N, 1024/16), 256, 0, stream>>>(f_buf, W_[4], as_[4], ad_[4], es, ed, Hb, N);
  agg_k<2,8><<<gb, 256, 0, stream>>>(csr_src, row_off, es, ed, Hb, b_[4], f_buf, N);

  // global mean pool (G=64) + FC + sigmoid
  hipMemsetAsync(pooled, 0, (64 * 16 + 64) * 4, stream);
  pool_k<<<64, 256, 0, stream>>>(f_buf, batch, pooled, cnt, N);
  final_fc_k<<<1, 64, 0, stream>>>(pooled, cnt, fcW, fcb, outp);
}

// Round 8
// 542.438 us; speedup vs baseline: 5.7501x; 1.2776x over previous
//
#include <hip/hip_runtime.h>
#include <math.h>

#define TPB 256
#define NEG_SLOPE 0.2f
#define SCAN_T 1024
#define EPB 2048          // edges per block-chunk in sliced CSR kernels

static inline int cdiv_l(long a, int b){ return (int)((a + b - 1) / b); }

__device__ __forceinline__ ushort f2bf(float f){
  unsigned u = __float_as_uint(f);
  unsigned r = u + 0x7fffu + ((u >> 16) & 1u);   // RNE
  return (ushort)(r >> 16);
}
__device__ __forceinline__ float bf2f(unsigned hi16){ return __uint_as_float(hi16 << 16); }

// ---------------- GEMM + fused attention dots + bf16 payload write ----------------
template<int Fin, int HC, int C>
__global__ __launch_bounds__(256) void gemm2_k(const float* __restrict__ X,
        const float* __restrict__ W, const float* __restrict__ as_,
        const float* __restrict__ ad_, float* __restrict__ es, float* __restrict__ ed,
        ushort* __restrict__ Hb, int N){
  constexpr int TPN = HC / 4;         // threads per node
  constexpr int NPB = 256 / TPN;      // nodes per block
  constexpr int H   = HC / C;
  constexpr int RG  = C / 4;          // lanes per (node, head)
  __shared__ float Wl[Fin * HC];
  for (int i = threadIdx.x; i < Fin * HC; i += 256) Wl[i] = W[i];
  __syncthreads();
  const int t  = threadIdx.x;
  const int n  = blockIdx.x * NPB + t / TPN;
  const int jt = (t % TPN) * 4;
  if (n >= N) return;
  const float* xr = X + (size_t)n * Fin;
  float acc[4] = {0.f, 0.f, 0.f, 0.f};
  for (int k = 0; k < Fin; k += 4){
    float4 xv = *(const float4*)(xr + k);
#pragma unroll
    for (int kk = 0; kk < 4; ++kk){
      float xs = (&xv.x)[kk];
#pragma unroll
      for (int j = 0; j < 4; ++j)
        acc[j] = fmaf(xs, Wl[(k + kk) * HC + jt + j], acc[j]);
    }
  }
  ushort4 hb;
  hb.x = f2bf(acc[0]); hb.y = f2bf(acc[1]); hb.z = f2bf(acc[2]); hb.w = f2bf(acc[3]);
  *(ushort4*)(Hb + (size_t)n * HC + jt) = hb;
  const int head = jt / C, col = jt % C;
  float ps = 0.f, pd = 0.f;
#pragma unroll
  for (int j = 0; j < 4; ++j){
    ps = fmaf(acc[j], as_[head * C + col + j], ps);
    pd = fmaf(acc[j], ad_[head * C + col + j], pd);
  }
#pragma unroll
  for (int off = RG >> 1; off >= 1; off >>= 1){
    ps += __shfl_xor(ps, off);
    pd += __shfl_xor(pd, off);
  }
  if ((t % RG) == 0){
    es[n * H + head] = ps;
    ed[n * H + head] = pd;
  }
}

// ---------------- CSR build (XCD-sliced) ----------------

__global__ void fill1_k(int* __restrict__ p, int n){
  int i = blockIdx.x * TPB + threadIdx.x;
  if (i < n) p[i] = 1;                 // self-loop pre-counted
}

__global__ __launch_bounds__(256) void hist8_k(const int* __restrict__ dst,
                        int* __restrict__ count, int E, int nps){
  const int slice = blockIdx.x & 7;
  const int lo = slice * nps, hi = lo + nps;
  const int c0 = (blockIdx.x >> 3) * EPB;
  int i1 = c0 + EPB; if (i1 > E) i1 = E;
  for (int i = c0 + threadIdx.x; i < i1; i += TPB){
    int d = dst[i];
    if (d >= lo && d < hi) atomicAdd(&count[d], 1);
  }
}

__global__ void scan_k(const int* __restrict__ count, int* __restrict__ row_off, int N){
  __shared__ int part[SCAN_T];
  int t = threadIdx.x;
  int chunk = (N + SCAN_T - 1) / SCAN_T;
  int b0 = t * chunk, b1 = b0 + chunk; if (b1 > N) b1 = N; if (b0 > N) b0 = N;
  int s = 0;
  for (int i = b0; i < b1; ++i) s += count[i];
  part[t] = s; __syncthreads();
  for (int off = 1; off < SCAN_T; off <<= 1){
    int v = (t >= off) ? part[t - off] : 0;
    __syncthreads();
    part[t] += v;
    __syncthreads();
  }
  int excl = (t == 0) ? 0 : part[t - 1];
  for (int i = b0; i < b1; ++i){ row_off[i] = excl; excl += count[i]; }
  if (t == SCAN_T - 1) row_off[N] = excl;
}

__global__ void cursor_k(const int* __restrict__ row_off, int* __restrict__ cursor,
                         int* __restrict__ csr_src, int N){
  int i = blockIdx.x * TPB + threadIdx.x;
  if (i >= N) return;
  int r = row_off[i];
  csr_src[r] = i;          // self-loop occupies first slot
  cursor[i] = r + 1;
}

__global__ __launch_bounds__(256) void scatter8_k(const int* __restrict__ src,
                          const int* __restrict__ dst,
                          int* __restrict__ cursor, int* __restrict__ csr_src,
                          int E, int nps){
  const int slice = blockIdx.x & 7;
  const int lo = slice * nps, hi = lo + nps;
  const int c0 = (blockIdx.x >> 3) * EPB;
  int i1 = c0 + EPB; if (i1 > E) i1 = E;
  for (int i = c0 + threadIdx.x; i < i1; i += TPB){
    int d = dst[i];
    if (d >= lo && d < hi){
      int p = atomicAdd(&cursor[d], 1);
      csr_src[p] = src[i];
    }
  }
}

// ---------------- fused single-pass softmax + aggregate + bias + relu ----------------
// one wave per destination node; bf16 payload, fp32 accumulate.
// t = exp(min(leaky(es+ed),80)) (shift-free softmax); acc += t*h; den += t.
// Wide datapath: each lane owns 4 channels (dwordx2), LPE=HC/4 lanes per edge,
// EPW=64/LPE edges per wave-iteration. Invalid slots carry t=0 -> branch-free.

template<int H, int C>
__global__ __launch_bounds__(256) void agg_k(const int* __restrict__ csr_src,
        const int* __restrict__ row_off,
        const float* __restrict__ es, const float* __restrict__ ed,
        const ushort* __restrict__ Hb, const float* __restrict__ b,
        float* __restrict__ outp, int N){
  constexpr int HC  = H * C;
  constexpr int LPE = HC / 4;         // lanes per edge
  constexpr int EPW = 64 / LPE;       // edges per wave-iteration
  const int lane = threadIdx.x & 63;
  const int wv   = threadIdx.x >> 6;
  const int n = blockIdx.x * 4 + wv;
  if (n >= N) return;
  const int beg = row_off[n];
  const int deg = row_off[n + 1] - beg;

  const int grp  = lane / LPE;        // which edge slot this lane serves
  const int cpos = lane % LPE;        // which 4-channel group
  const int c0   = cpos * 4;
  const int hd   = c0 / C;            // head of this lane's channels (C%4==0)

  float edn[H];
#pragma unroll
  for (int h = 0; h < H; ++h) edn[h] = ed[n * H + h];

  float den[H];
#pragma unroll
  for (int h = 0; h < H; ++h) den[h] = 0.f;
  float acc[4] = {0.f, 0.f, 0.f, 0.f};

  for (int base = 0; base < deg; base += 64){
    int j = base + lane;
    float t[H]; int sidx = 0;
    if (j < deg){
      sidx = csr_src[beg + j];
      float ev[H];
      if (H == 2){
        float2 e2 = *(const float2*)(es + sidx * 2);
        ev[0] = e2.x; ev[1] = e2.y;
      } else ev[0] = es[sidx];
#pragma unroll
      for (int h = 0; h < H; ++h){
        float e = ev[h] + edn[h];
        e = e > 0.f ? e : e * NEG_SLOPE;
        e = fminf(e, 80.f);
        t[h] = __expf(e);
        den[h] += t[h];
      }
    } else {
#pragma unroll
      for (int h = 0; h < H; ++h) t[h] = 0.f;
    }
    int cnt = deg - base; if (cnt > 64) cnt = 64;

    for (int i = 0; i < cnt; i += EPW){
      int sl = i + grp;                       // edge slot for this lane (<64)
      int sj = __shfl(sidx, sl);              // t==0 masks any overrun slot
      float tf;
      if (H == 2){
        float t0 = __shfl(t[0], sl);
        float t1 = __shfl(t[1], sl);
        tf = hd ? t1 : t0;
      } else {
        tf = __shfl(t[0], sl);
      }
      const ushort* hr = Hb + (size_t)sj * HC + c0;
      uint2 v = *(const uint2*)hr;
      acc[0] = fmaf(tf, bf2f(v.x & 0xffffu), acc[0]);
      acc[1] = fmaf(tf, bf2f(v.x >> 16),     acc[1]);
      acc[2] = fmaf(tf, bf2f(v.y & 0xffffu), acc[2]);
      acc[3] = fmaf(tf, bf2f(v.y >> 16),     acc[3]);
    }
  }

  // reduce denominators across the wave
  float sinv[H];
#pragma unroll
  for (int h = 0; h < H; ++h){
    float v = den[h];
#pragma unroll
    for (int off = 32; off >= 1; off >>= 1) v += __shfl_xor(v, off);
    sinv[h] = 1.f / v;
  }

  // reduce partial channel sums across edge-slot groups
#pragma unroll
  for (int off = LPE; off < 64; off <<= 1){
#pragma unroll
    for (int k = 0; k < 4; ++k) acc[k] += __shfl_xor(acc[k], off);
  }

  if (grp == 0){
    float4 bv = *(const float4*)(b + c0);
    float si = sinv[hd];
    float4 o;
    o.x = fmaf(acc[0], si, bv.x); o.x = o.x > 0.f ? o.x : 0.f;
    o.y = fmaf(acc[1], si, bv.y); o.y = o.y > 0.f ? o.y : 0.f;
    o.z = fmaf(acc[2], si, bv.z); o.z = o.z > 0.f ? o.z : 0.f;
    o.w = fmaf(acc[3], si, bv.w); o.w = o.w > 0.f ? o.w : 0.f;
    *(float4*)(outp + (size_t)n * HC + c0) = o;
  }
}

// ---------------- pooling + FC ----------------

__global__ __launch_bounds__(256) void pool_k(const float* __restrict__ f,
                       const int* __restrict__ batch,
                       float* __restrict__ pooled, float* __restrict__ cnt, int N){
  __shared__ float sp[64 * 16];
  __shared__ float sc[64];
  const int t = threadIdx.x;
  for (int i = t; i < 64 * 16; i += 256) sp[i] = 0.f;
  for (int i = t; i < 64; i += 256) sc[i] = 0.f;
  __syncthreads();
  const int per = (N + gridDim.x - 1) / gridDim.x;
  const int n0 = blockIdx.x * per;
  int n1 = n0 + per; if (n1 > N) n1 = N;
  const int nloc = t >> 4, c = t & 15;
  for (int n = n0 + nloc; n < n1; n += 16){
    int g = batch[n];
    atomicAdd(&sp[g * 16 + c], f[(size_t)n * 16 + c]);
    if (c == 0) atomicAdd(&sc[g], 1.f);
  }
  __syncthreads();
  for (int i = t; i < 64 * 16; i += 256) if (sp[i] != 0.f) atomicAdd(&pooled[i], sp[i]);
  for (int i = t; i < 64; i += 256)      if (sc[i] != 0.f) atomicAdd(&cnt[i], sc[i]);
}

__global__ void final_fc_k(const float* __restrict__ pooled, const float* __restrict__ cnt,
                           const float* __restrict__ fcW, const float* __restrict__ fcb,
                           float* __restrict__ outp){
  int g = threadIdx.x;
  if (g >= 64) return;
  float c = cnt[g]; c = c > 1.f ? c : 1.f;
  float inv = 1.0f / c;
  float acc = fcb[0];
  for (int i = 0; i < 16; ++i) acc = fmaf(pooled[g * 16 + i] * inv, fcW[i], acc);
  outp[g] = 1.0f / (1.0f + expf(-acc));
}

// ---------------- driver ----------------

extern "C" void kernel_launch(void* const* d_in, const int* in_sizes, int n_in,
                              void* d_out, int out_size, void* d_ws, size_t ws_size,
                              hipStream_t stream) {
  const float* x    = (const float*)d_in[0];
  const int*  ei    = (const int*)d_in[1];
  const int*  batch = (const int*)d_in[2];

  const int N = in_sizes[0] / 128;
  const int E = in_sizes[1] / 2;

  const int* src = ei;
  const int* dst = ei + E;

  const float* W_[5];  const float* as_[5]; const float* ad_[5]; const float* b_[5];
  for (int l = 0; l < 5; ++l) {
    W_[l]  = (const float*)d_in[3 + 4 * l + 0];
    as_[l] = (const float*)d_in[3 + 4 * l + 1];
    ad_[l] = (const float*)d_in[3 + 4 * l + 2];
    b_[l]  = (const float*)d_in[3 + 4 * l + 3];
  }
  const float* fcW = (const float*)d_in[23];
  const float* fcb = (const float*)d_in[24];
  float* outp = (float*)d_out;

  // workspace layout
  float*  f_buf  = (float*)d_ws;                       // N*128 fp32 (layer output)
  ushort* Hb     = (ushort*)(f_buf + (size_t)N * 128); // N*128 bf16 payload
  float*  es     = (float*)(Hb + (size_t)N * 128);     // N*2
  float*  ed     = es + (size_t)N * 2;                 // N*2
  float*  pooled = ed + (size_t)N * 2;                 // 64*16
  float*  cnt    = pooled + 64 * 16;                   // 64
  int*    count  = (int*)(cnt + 64);                   // N
  int*    row_off= count + N;                          // N+1
  int*    cursor = row_off + N + 1;                    // N
  int*    csr_src= cursor + N;                         // E+N

  // ---- build CSR by destination (XCD-sliced; reused by all 5 layers) ----
  const int nps = (N + 7) / 8;                     // nodes per dst-slice
  const int nch = cdiv_l(E, EPB);                  // edge chunks
  fill1_k<<<cdiv_l(N, TPB), TPB, 0, stream>>>(count, N);
  hist8_k<<<nch * 8, TPB, 0, stream>>>(dst, count, E, nps);
  scan_k<<<1, SCAN_T, 0, stream>>>(count, row_off, N);
  cursor_k<<<cdiv_l(N, TPB), TPB, 0, stream>>>(row_off, cursor, csr_src, N);
  scatter8_k<<<nch * 8, TPB, 0, stream>>>(src, dst, cursor, csr_src, E, nps);

  const float* X = x;
  const int gb = cdiv_l(N, 4);

  // layer 1: Fin=128, H=1, C=32
  gemm2_k<128,32,32><<<cdiv_l(N, 1024/32), 256, 0, stream>>>(X, W_[0], as_[0], ad_[0], es, ed, Hb, N);
  agg_k<1,32><<<gb, 256, 0, stream>>>(csr_src, row_off, es, ed, Hb, b_[0], f_buf, N);
  // layer 2: Fin=32, H=2, C=32
  gemm2_k<32,64,32><<<cdiv_l(N, 1024/64), 256, 0, stream>>>(f_buf, W_[1], as_[1], ad_[1], es, ed, Hb, N);
  agg_k<2,32><<<gb, 256, 0, stream>>>(csr_src, row_off, es, ed, Hb, b_[1], f_buf, N);
  // layer 3: Fin=64, H=2, C=64
  gemm2_k<64,128,64><<<cdiv_l(N, 1024/128), 256, 0, stream>>>(f_buf, W_[2], as_[2], ad_[2], es, ed, Hb, N);
  agg_k<2,64><<<gb, 256, 0, stream>>>(csr_src, row_off, es, ed, Hb, b_[2], f_buf, N);
  // layer 4: Fin=128, H=2, C=32
  gemm2_k<128,64,32><<<cdiv_l(N, 1024/64), 256, 0, stream>>>(f_buf, W_[3], as_[3], ad_[3], es, ed, Hb, N);
  agg_k<2,32><<<gb, 256, 0, stream>>>(csr_src, row_off, es, ed, Hb, b_[3], f_buf, N);
  // layer 5: Fin=64, H=2, C=8
  gemm2_k<64,16,8><<<cdiv_l(N, 1024/16), 256, 0, stream>>>(f_buf, W_[4], as_[4], ad_[4], es, ed, Hb, N);
  agg_k<2,8><<<gb, 256, 0, stream>>>(csr_src, row_off, es, ed, Hb, b_[4], f_buf, N);

  // global mean pool (G=64) + FC + sigmoid
  hipMemsetAsync(pooled, 0, (64 * 16 + 64) * 4, stream);
  pool_k<<<64, 256, 0, stream>>>(f_buf, batch, pooled, cnt, N);
  final_fc_k<<<1, 64, 0, stream>>>(pooled, cnt, fcW, fcb, outp);
}

// Round 9
// 542.282 us; speedup vs baseline: 5.7518x; 1.0003x over previous
//
#include <hip/hip_runtime.h>
#include <math.h>

#define TPB 256
#define NEG_SLOPE 0.2f
#define SCAN_T 1024
#define EPB 2048          // edges per block-chunk in sliced CSR kernels

static inline int cdiv_l(long a, int b){ return (int)((a + b - 1) / b); }

__device__ __forceinline__ ushort f2bf(float f){
  unsigned u = __float_as_uint(f);
  unsigned r = u + 0x7fffu + ((u >> 16) & 1u);   // RNE
  return (ushort)(r >> 16);
}
__device__ __forceinline__ float bf2f(unsigned hi16){ return __uint_as_float(hi16 << 16); }

// ---------------- GEMM + fused attention dots + bf16 payload write ----------------
template<int Fin, int HC, int C>
__global__ __launch_bounds__(256) void gemm2_k(const float* __restrict__ X,
        const float* __restrict__ W, const float* __restrict__ as_,
        const float* __restrict__ ad_, float* __restrict__ es, float* __restrict__ ed,
        ushort* __restrict__ Hb, int N){
  constexpr int TPN = HC / 4;         // threads per node
  constexpr int NPB = 256 / TPN;      // nodes per block
  constexpr int H   = HC / C;
  constexpr int RG  = C / 4;          // lanes per (node, head)
  __shared__ float Wl[Fin * HC];
  for (int i = threadIdx.x; i < Fin * HC; i += 256) Wl[i] = W[i];
  __syncthreads();
  const int t  = threadIdx.x;
  const int n  = blockIdx.x * NPB + t / TPN;
  const int jt = (t % TPN) * 4;
  if (n >= N) return;
  const float* xr = X + (size_t)n * Fin;
  float acc[4] = {0.f, 0.f, 0.f, 0.f};
  for (int k = 0; k < Fin; k += 4){
    float4 xv = *(const float4*)(xr + k);
#pragma unroll
    for (int kk = 0; kk < 4; ++kk){
      float xs = (&xv.x)[kk];
#pragma unroll
      for (int j = 0; j < 4; ++j)
        acc[j] = fmaf(xs, Wl[(k + kk) * HC + jt + j], acc[j]);
    }
  }
  ushort4 hb;
  hb.x = f2bf(acc[0]); hb.y = f2bf(acc[1]); hb.z = f2bf(acc[2]); hb.w = f2bf(acc[3]);
  *(ushort4*)(Hb + (size_t)n * HC + jt) = hb;
  const int head = jt / C, col = jt % C;
  float ps = 0.f, pd = 0.f;
#pragma unroll
  for (int j = 0; j < 4; ++j){
    ps = fmaf(acc[j], as_[head * C + col + j], ps);
    pd = fmaf(acc[j], ad_[head * C + col + j], pd);
  }
#pragma unroll
  for (int off = RG >> 1; off >= 1; off >>= 1){
    ps += __shfl_xor(ps, off);
    pd += __shfl_xor(pd, off);
  }
  if ((t % RG) == 0){
    es[n * H + head] = ps;
    ed[n * H + head] = pd;
  }
}

// ---------------- CSR build (XCD-sliced, non-temporal edge streaming) ----------------

// block b: edge chunk b>>3, dst slice b&7. Round-robin dispatch => slice-local
// atomics/writes stay within one XCD's L2; nt loads keep the streamed edge
// list from evicting the partially-filled scatter lines.
__global__ __launch_bounds__(256) void hist8_k(const int* __restrict__ dst,
                        int* __restrict__ count, int E, int nps){
  const int slice = blockIdx.x & 7;
  const int lo = slice * nps, hi = lo + nps;
  const int c0 = (blockIdx.x >> 3) * EPB;
  int i1 = c0 + EPB; if (i1 > E) i1 = E;
  for (int i = c0 + threadIdx.x; i < i1; i += TPB){
    int d = __builtin_nontemporal_load(dst + i);
    if (d >= lo && d < hi) atomicAdd(&count[d], 1);
  }
}

// single-block exclusive scan; +1 per node folds in the self-loop
__global__ void scan_k(const int* __restrict__ count, int* __restrict__ row_off, int N){
  __shared__ int part[SCAN_T];
  int t = threadIdx.x;
  int chunk = (N + SCAN_T - 1) / SCAN_T;
  int b0 = t * chunk, b1 = b0 + chunk; if (b1 > N) b1 = N; if (b0 > N) b0 = N;
  int s = 0;
  for (int i = b0; i < b1; ++i) s += count[i] + 1;
  part[t] = s; __syncthreads();
  for (int off = 1; off < SCAN_T; off <<= 1){
    int v = (t >= off) ? part[t - off] : 0;
    __syncthreads();
    part[t] += v;
    __syncthreads();
  }
  int excl = (t == 0) ? 0 : part[t - 1];
  for (int i = b0; i < b1; ++i){ row_off[i] = excl; excl += count[i] + 1; }
  if (t == SCAN_T - 1) row_off[N] = excl;
}

__global__ void cursor_k(const int* __restrict__ row_off, int* __restrict__ cursor,
                         int* __restrict__ csr_src, int N){
  int i = blockIdx.x * TPB + threadIdx.x;
  if (i >= N) return;
  int r = row_off[i];
  csr_src[r] = i;          // self-loop occupies first slot
  cursor[i] = r + 1;
}

__global__ __launch_bounds__(256) void scatter8_k(const int* __restrict__ src,
                          const int* __restrict__ dst,
                          int* __restrict__ cursor, int* __restrict__ csr_src,
                          int E, int nps){
  const int slice = blockIdx.x & 7;
  const int lo = slice * nps, hi = lo + nps;
  const int c0 = (blockIdx.x >> 3) * EPB;
  int i1 = c0 + EPB; if (i1 > E) i1 = E;
  for (int i = c0 + threadIdx.x; i < i1; i += TPB){
    int d = __builtin_nontemporal_load(dst + i);
    if (d >= lo && d < hi){
      int s = __builtin_nontemporal_load(src + i);
      int p = atomicAdd(&cursor[d], 1);
      csr_src[p] = s;
    }
  }
}

// ---------------- fused single-pass softmax + aggregate + bias + relu ----------------
// one wave per destination node; bf16 payload, fp32 accumulate.
// t = exp(min(leaky(es+ed),80)) (shift-free softmax); acc += t*h; den += t.
// Wide datapath: each lane owns 4 channels (dwordx2), LPE=HC/4 lanes per edge,
// EPW=64/LPE edges per wave-iteration. Invalid slots carry t=0 -> branch-free.

template<int H, int C>
__global__ __launch_bounds__(256) void agg_k(const int* __restrict__ csr_src,
        const int* __restrict__ row_off,
        const float* __restrict__ es, const float* __restrict__ ed,
        const ushort* __restrict__ Hb, const float* __restrict__ b,
        float* __restrict__ outp, int N){
  constexpr int HC  = H * C;
  constexpr int LPE = HC / 4;         // lanes per edge
  constexpr int EPW = 64 / LPE;       // edges per wave-iteration
  const int lane = threadIdx.x & 63;
  const int wv   = threadIdx.x >> 6;
  const int n = blockIdx.x * 4 + wv;
  if (n >= N) return;
  const int beg = row_off[n];
  const int deg = row_off[n + 1] - beg;

  const int grp  = lane / LPE;        // which edge slot this lane serves
  const int cpos = lane % LPE;        // which 4-channel group
  const int c0   = cpos * 4;
  const int hd   = c0 / C;            // head of this lane's channels (C%4==0)

  float edn[H];
#pragma unroll
  for (int h = 0; h < H; ++h) edn[h] = ed[n * H + h];

  float den[H];
#pragma unroll
  for (int h = 0; h < H; ++h) den[h] = 0.f;
  float acc[4] = {0.f, 0.f, 0.f, 0.f};

  for (int base = 0; base < deg; base += 64){
    int j = base + lane;
    float t[H]; int sidx = 0;
    if (j < deg){
      sidx = csr_src[beg + j];
      float ev[H];
      if (H == 2){
        float2 e2 = *(const float2*)(es + sidx * 2);
        ev[0] = e2.x; ev[1] = e2.y;
      } else ev[0] = es[sidx];
#pragma unroll
      for (int h = 0; h < H; ++h){
        float e = ev[h] + edn[h];
        e = e > 0.f ? e : e * NEG_SLOPE;
        e = fminf(e, 80.f);
        t[h] = __expf(e);
        den[h] += t[h];
      }
    } else {
#pragma unroll
      for (int h = 0; h < H; ++h) t[h] = 0.f;
    }
    int cnt = deg - base; if (cnt > 64) cnt = 64;

    for (int i = 0; i < cnt; i += EPW){
      int sl = i + grp;                       // edge slot for this lane (<64)
      int sj = __shfl(sidx, sl);              // t==0 masks any overrun slot
      float tf;
      if (H == 2){
        float t0 = __shfl(t[0], sl);
        float t1 = __shfl(t[1], sl);
        tf = hd ? t1 : t0;
      } else {
        tf = __shfl(t[0], sl);
      }
      const ushort* hr = Hb + (size_t)sj * HC + c0;
      uint2 v = *(const uint2*)hr;
      acc[0] = fmaf(tf, bf2f(v.x & 0xffffu), acc[0]);
      acc[1] = fmaf(tf, bf2f(v.x >> 16),     acc[1]);
      acc[2] = fmaf(tf, bf2f(v.y & 0xffffu), acc[2]);
      acc[3] = fmaf(tf, bf2f(v.y >> 16),     acc[3]);
    }
  }

  // reduce denominators across the wave
  float sinv[H];
#pragma unroll
  for (int h = 0; h < H; ++h){
    float v = den[h];
#pragma unroll
    for (int off = 32; off >= 1; off >>= 1) v += __shfl_xor(v, off);
    sinv[h] = 1.f / v;
  }

  // reduce partial channel sums across edge-slot groups
#pragma unroll
  for (int off = LPE; off < 64; off <<= 1){
#pragma unroll
    for (int k = 0; k < 4; ++k) acc[k] += __shfl_xor(acc[k], off);
  }

  if (grp == 0){
    float4 bv = *(const float4*)(b + c0);
    float si = sinv[hd];
    float4 o;
    o.x = fmaf(acc[0], si, bv.x); o.x = o.x > 0.f ? o.x : 0.f;
    o.y = fmaf(acc[1], si, bv.y); o.y = o.y > 0.f ? o.y : 0.f;
    o.z = fmaf(acc[2], si, bv.z); o.z = o.z > 0.f ? o.z : 0.f;
    o.w = fmaf(acc[3], si, bv.w); o.w = o.w > 0.f ? o.w : 0.f;
    *(float4*)(outp + (size_t)n * HC + c0) = o;
  }
}

// ---------------- pooling + FC ----------------

__global__ __launch_bounds__(256) void pool_k(const float* __restrict__ f,
                       const int* __restrict__ batch,
                       float* __restrict__ pooled, float* __restrict__ cnt, int N){
  __shared__ float sp[64 * 16];
  __shared__ float sc[64];
  const int t = threadIdx.x;
  for (int i = t; i < 64 * 16; i += 256) sp[i] = 0.f;
  for (int i = t; i < 64; i += 256) sc[i] = 0.f;
  __syncthreads();
  const int per = (N + gridDim.x - 1) / gridDim.x;
  const int n0 = blockIdx.x * per;
  int n1 = n0 + per; if (n1 > N) n1 = N;
  const int nloc = t >> 4, c = t & 15;
  for (int n = n0 + nloc; n < n1; n += 16){
    int g = batch[n];
    atomicAdd(&sp[g * 16 + c], f[(size_t)n * 16 + c]);
    if (c == 0) atomicAdd(&sc[g], 1.f);
  }
  __syncthreads();
  for (int i = t; i < 64 * 16; i += 256) if (sp[i] != 0.f) atomicAdd(&pooled[i], sp[i]);
  for (int i = t; i < 64; i += 256)      if (sc[i] != 0.f) atomicAdd(&cnt[i], sc[i]);
}

__global__ void final_fc_k(const float* __restrict__ pooled, const float* __restrict__ cnt,
                           const float* __restrict__ fcW, const float* __restrict__ fcb,
                           float* __restrict__ outp){
  int g = threadIdx.x;
  if (g >= 64) return;
  float c = cnt[g]; c = c > 1.f ? c : 1.f;
  float inv = 1.0f / c;
  float acc = fcb[0];
  for (int i = 0; i < 16; ++i) acc = fmaf(pooled[g * 16 + i] * inv, fcW[i], acc);
  outp[g] = 1.0f / (1.0f + expf(-acc));
}

// ---------------- driver ----------------

extern "C" void kernel_launch(void* const* d_in, const int* in_sizes, int n_in,
                              void* d_out, int out_size, void* d_ws, size_t ws_size,
                              hipStream_t stream) {
  const float* x    = (const float*)d_in[0];
  const int*  ei    = (const int*)d_in[1];
  const int*  batch = (const int*)d_in[2];

  const int N = in_sizes[0] / 128;
  const int E = in_sizes[1] / 2;

  const int* src = ei;
  const int* dst = ei + E;

  const float* W_[5];  const float* as_[5]; const float* ad_[5]; const float* b_[5];
  for (int l = 0; l < 5; ++l) {
    W_[l]  = (const float*)d_in[3 + 4 * l + 0];
    as_[l] = (const float*)d_in[3 + 4 * l + 1];
    ad_[l] = (const float*)d_in[3 + 4 * l + 2];
    b_[l]  = (const float*)d_in[3 + 4 * l + 3];
  }
  const float* fcW = (const float*)d_in[23];
  const float* fcb = (const float*)d_in[24];
  float* outp = (float*)d_out;

  // workspace layout
  float*  f_buf  = (float*)d_ws;                       // N*128 fp32 (layer output)
  ushort* Hb     = (ushort*)(f_buf + (size_t)N * 128); // N*128 bf16 payload
  float*  es     = (float*)(Hb + (size_t)N * 128);     // N*2
  float*  ed     = es + (size_t)N * 2;                 // N*2
  float*  pooled = ed + (size_t)N * 2;                 // 64*16
  float*  cnt    = pooled + 64 * 16;                   // 64
  int*    count  = (int*)(cnt + 64);                   // N
  int*    row_off= count + N;                          // N+1
  int*    cursor = row_off + N + 1;                    // N
  int*    csr_src= cursor + N;                         // E+N

  // ---- build CSR by destination (XCD-sliced; reused by all 5 layers) ----
  const int nps = (N + 7) / 8;                     // nodes per dst-slice
  const int nch = cdiv_l(E, EPB);                  // edge chunks
  hipMemsetAsync(count, 0, (size_t)N * 4, stream);
  hist8_k<<<nch * 8, TPB, 0, stream>>>(dst, count, E, nps);
  scan_k<<<1, SCAN_T, 0, stream>>>(count, row_off, N);
  cursor_k<<<cdiv_l(N, TPB), TPB, 0, stream>>>(row_off, cursor, csr_src, N);
  scatter8_k<<<nch * 8, TPB, 0, stream>>>(src, dst, cursor, csr_src, E, nps);

  const float* X = x;
  const int gb = cdiv_l(N, 4);

  // layer 1: Fin=128, H=1, C=32
  gemm2_k<128,32,32><<<cdiv_l(N, 1024/32), 256, 0, stream>>>(X, W_[0], as_[0], ad_[0], es, ed, Hb, N);
  agg_k<1,32><<<gb, 256, 0, stream>>>(csr_src, row_off, es, ed, Hb, b_[0], f_buf, N);
  // layer 2: Fin=32, H=2, C=32
  gemm2_k<32,64,32><<<cdiv_l(N, 1024/64), 256, 0, stream>>>(f_buf, W_[1], as_[1], ad_[1], es, ed, Hb, N);
  agg_k<2,32><<<gb, 256, 0, stream>>>(csr_src, row_off, es, ed, Hb, b_[1], f_buf, N);
  // layer 3: Fin=64, H=2, C=64
  gemm2_k<64,128,64><<<cdiv_l(N, 1024/128), 256, 0, stream>>>(f_buf, W_[2], as_[2], ad_[2], es, ed, Hb, N);
  agg_k<2,64><<<gb, 256, 0, stream>>>(csr_src, row_off, es, ed, Hb, b_[2], f_buf, N);
  // layer 4: Fin=128, H=2, C=32
  gemm2_k<128,64,32><<<cdiv_l(N, 1024/64), 256, 0, stream>>>(f_buf, W_[3], as_[3], ad_[3], es, ed, Hb, N);
  agg_k<2,32><<<gb, 256, 0, stream>>>(csr_src, row_off, es, ed, Hb, b_[3], f_buf, N);
  // layer 5: Fin=64, H=2, C=8
  gemm2_k<64,16,8><<<cdiv_l(N, 1024/16), 256, 0, stream>>>(f_buf, W_[4], as_[4], ad_[4], es, ed, Hb, N);
  agg_k<2,8><<<gb, 256, 0, stream>>>(csr_src, row_off, es, ed, Hb, b_[4], f_buf, N);

  // global mean pool (G=64) + FC + sigmoid
  hipMemsetAsync(pooled, 0, (64 * 16 + 64) * 4, stream);
  pool_k<<<64, 256, 0, stream>>>(f_buf, batch, pooled, cnt, N);
  final_fc_k<<<1, 64, 0, stream>>>(pooled, cnt, fcW, fcb, outp);
}